// Round 11
// baseline (193.943 us; speedup 1.0000x reference)
//
#include <hip/hip_runtime.h>

#define NN 50000
#define NE 1600000
#define DIM 256
#define OUTD 64
#define ALPHA 0.2f

#define BSH 5                  // bucket = src >> 5 (32 nodes/bucket)
#define NB ((NN + 31) >> 5)    // 1563 buckets
#define NCLS 8                 // writer classes (= XCDs, blockIdx & 7)
#define SUBCAP 256             // per-(bucket,class) capacity (mean 128, +11s)
#define CAP (NCLS * SUBCAP)    // 2048 per bucket
#define P1 500                 // binning blocks (class-split -> no XCD bounce)
#define EPB (NE / P1)          // 3200 edges per block (div by 4)

#define GEMM_BLOCKS ((NN + 63) / 64)  // 782 (64 rows/block = 16 rows x 4 waves)
#define WSTRIDE 264            // Wl LDS row stride in u16 (256 + 8 pad)
#define ZB 49                  // zero-blocks: NB*NCLS = 12504 ints

typedef unsigned short u16;
typedef unsigned int u32;
typedef __attribute__((ext_vector_type(8))) short short8;   // 8 bf16 MFMA frag
typedef __attribute__((ext_vector_type(4))) float floatx4;  // MFMA accum

__device__ __forceinline__ u16 f2bf(float f) {
  u32 b = __float_as_uint(f);
  b += 0x7FFFu + ((b >> 16) & 1u);  // RNE
  return (u16)(b >> 16);
}
__device__ __forceinline__ float bflo(u32 u) { return __uint_as_float(u << 16); }
__device__ __forceinline__ float bfhi(u32 u) { return __uint_as_float(u & 0xFFFF0000u); }

// ---------------------------------------------------------------------------
// init: blocks [0,ZB) zero per-(bucket,class) counters; blocks [ZB,ZB+32)
// build W^T bf16 pairs (wt[n*128+kp] = {k=2kp lo, k=2kp+1 hi}).
// ---------------------------------------------------------------------------
__global__ __launch_bounds__(256) void init_kernel(const float* __restrict__ W,
                                                   u32* __restrict__ wt,
                                                   int* __restrict__ bktcnt) {
  if (blockIdx.x < ZB) {
    const int i = blockIdx.x * 256 + threadIdx.x;
    if (i < NB * NCLS) bktcnt[i] = 0;
    return;
  }
  const int g = (blockIdx.x - ZB) * 256 + threadIdx.x;  // 0..8191
  const int n = g >> 7;
  const int kp = g & 127;
  const float lo = W[(size_t)(2 * kp) * OUTD + n];
  const float hi = W[(size_t)(2 * kp + 1) * OUTD + n];
  wt[g] = (u32)f2bf(lo) | ((u32)f2bf(hi) << 16);
}

// ---------------------------------------------------------------------------
// GEMM kernel (proven): bf16 MFMA h = x@W, packed bf16 out, s1/s2 epilogue.
// ---------------------------------------------------------------------------
__global__ __launch_bounds__(256) void gemm_kernel(
    const float* __restrict__ x, const u32* __restrict__ wt,
    const float* __restrict__ a, u16* __restrict__ hb,
    float* __restrict__ s1, float* __restrict__ s2)
{
  __shared__ u16 Wl[OUTD * WSTRIDE];  // 33 KB
  const int t = threadIdx.x;
  {  // stage W^T: 2048 uint4 chunks, coalesced global read, padded LDS write
    const uint4* srcv = (const uint4*)wt;
#pragma unroll
    for (int i = 0; i < 8; ++i) {
      const int c = t + 256 * i;
      const int n = c >> 5;
      const int k8 = c & 31;
      *(uint4*)&Wl[n * WSTRIDE + k8 * 8] = srcv[c];
    }
  }
  __syncthreads();

  const int lane = t & 63;
  const int wv = t >> 6;
  const int n = lane & 15;
  const int quad = lane >> 4;
  int rb = blockIdx.x * 64 + wv * 16;
  if (rb > NN - 16) rb = NN - 16;  // tail clamp (dup waves store identical)
  const int row = rb + n;
  const float4* xrow = (const float4*)(x + (size_t)row * DIM);

  floatx4 acc[4] = {{0.f, 0.f, 0.f, 0.f},
                    {0.f, 0.f, 0.f, 0.f},
                    {0.f, 0.f, 0.f, 0.f},
                    {0.f, 0.f, 0.f, 0.f}};

#pragma unroll
  for (int kk = 0; kk < 8; ++kk) {
    const float4 lo = xrow[kk * 8 + quad * 2];
    const float4 hi = xrow[kk * 8 + quad * 2 + 1];
    union { u32 u[4]; short8 s; } af;
    af.u[0] = (u32)f2bf(lo.x) | ((u32)f2bf(lo.y) << 16);
    af.u[1] = (u32)f2bf(lo.z) | ((u32)f2bf(lo.w) << 16);
    af.u[2] = (u32)f2bf(hi.x) | ((u32)f2bf(hi.y) << 16);
    af.u[3] = (u32)f2bf(hi.z) | ((u32)f2bf(hi.w) << 16);
#pragma unroll
    for (int nt = 0; nt < 4; ++nt) {
      const short8 bf =
          *(const short8*)&Wl[(nt * 16 + n) * WSTRIDE + kk * 32 + quad * 8];
      acc[nt] = __builtin_amdgcn_mfma_f32_16x16x32_bf16(af.s, bf, acc[nt], 0, 0, 0);
    }
  }

  float av1[4], av2[4];
#pragma unroll
  for (int nt = 0; nt < 4; ++nt) {
    av1[nt] = a[nt * 16 + n];
    av2[nt] = a[OUTD + nt * 16 + n];
  }

#pragma unroll
  for (int reg = 0; reg < 4; ++reg) {
    const int r = rb + quad * 4 + reg;
    float q1 = acc[0][reg] * av1[0] + acc[1][reg] * av1[1] +
               acc[2][reg] * av1[2] + acc[3][reg] * av1[3];
    float q2 = acc[0][reg] * av2[0] + acc[1][reg] * av2[1] +
               acc[2][reg] * av2[2] + acc[3][reg] * av2[3];
#pragma unroll
    for (int off = 1; off <= 8; off <<= 1) {
      q1 += __shfl_xor(q1, off);
      q2 += __shfl_xor(q2, off);
    }
    if (n == 0) { s1[r] = q1; s2[r] = q2; }
#pragma unroll
    for (int nt = 0; nt < 4; ++nt)
      hb[(size_t)r * OUTD + nt * 16 + n] = f2bf(acc[nt][reg]);
  }
}

// ---------------------------------------------------------------------------
// Bin kernel, XCD-class-partitioned: block p writes ONLY class cls = p & 7
// sub-regions. Writers of any cache line share a class -> (round-robin
// blockIdx->XCD mapping) same XCD -> no cross-XCD line bouncing, at ANY P1.
// P1=500 x 256 thr restores wave parallelism lost to the old P1 dilemma.
// ---------------------------------------------------------------------------
__global__ __launch_bounds__(256) void bin_kernel(
    const int* __restrict__ src, const int* __restrict__ dst,
    int* __restrict__ bktcnt, u32* __restrict__ binned)
{
  __shared__ int lh[NB];  // 6.25 KB
  const int t = threadIdx.x;
  const int p = blockIdx.x;
  const int cls = p & (NCLS - 1);
  for (int i = t; i < NB; i += 256) lh[i] = 0;
  __syncthreads();

  const int4* src4 = (const int4*)(src + p * EPB);
  const int4* dst4 = (const int4*)(dst + p * EPB);
  for (int i = t; i < EPB / 4; i += 256) {
    const int4 s = src4[i];
    if ((u32)s.x < (u32)NN) atomicAdd(&lh[s.x >> BSH], 1);
    if ((u32)s.y < (u32)NN) atomicAdd(&lh[s.y >> BSH], 1);
    if ((u32)s.z < (u32)NN) atomicAdd(&lh[s.z >> BSH], 1);
    if ((u32)s.w < (u32)NN) atomicAdd(&lh[s.w >> BSH], 1);
  }
  __syncthreads();

  // reserve a chunk in this block's class sub-region of each touched bucket;
  // lh becomes the absolute write cursor.
  for (int b = t; b < NB; b += 256) {
    const int c = lh[b];
    lh[b] = (c > 0)
        ? (b * NCLS + cls) * SUBCAP + atomicAdd(bktcnt + b * NCLS + cls, c)
        : 0;
  }
  __syncthreads();

  for (int i = t; i < EPB / 4; i += 256) {
    const int4 s = src4[i];
    const int4 d = dst4[i];
    int pos, b;
    if ((u32)s.x < (u32)NN) {
      b = s.x >> BSH; pos = atomicAdd(&lh[b], 1);
      if (pos < (b * NCLS + cls + 1) * SUBCAP)
        binned[pos] = ((u32)(s.x & 31) << 16) | (u32)(d.x & 0xFFFF);
    }
    if ((u32)s.y < (u32)NN) {
      b = s.y >> BSH; pos = atomicAdd(&lh[b], 1);
      if (pos < (b * NCLS + cls + 1) * SUBCAP)
        binned[pos] = ((u32)(s.y & 31) << 16) | (u32)(d.y & 0xFFFF);
    }
    if ((u32)s.z < (u32)NN) {
      b = s.z >> BSH; pos = atomicAdd(&lh[b], 1);
      if (pos < (b * NCLS + cls + 1) * SUBCAP)
        binned[pos] = ((u32)(s.z & 31) << 16) | (u32)(d.z & 0xFFFF);
    }
    if ((u32)s.w < (u32)NN) {
      b = s.w >> BSH; pos = atomicAdd(&lh[b], 1);
      if (pos < (b * NCLS + cls + 1) * SUBCAP)
        binned[pos] = ((u32)(s.w & 31) << 16) | (u32)(d.w & 0xFFFF);
    }
  }
}

// ---------------------------------------------------------------------------
// Fused group+agg (proven round-10 phases + 8-sub-run compaction): one
// 256-thread block per 32-node bucket. Compact the 8 class sub-runs into
// LDS -> count -> 32-wide scan -> scatter (weight exp fused) -> 4 waves x
// 8 nodes register-accumulator gather with LDS broadcast of (d, w).
// ---------------------------------------------------------------------------
__global__ __launch_bounds__(256) void bucket_agg_kernel(
    const u16* __restrict__ hb, const float* __restrict__ s1,
    const float* __restrict__ s2, const int* __restrict__ bktcnt,
    const u32* __restrict__ binned, float* __restrict__ out)
{
  __shared__ u32 ebuf[CAP];    // 8 KB compacted bucket edges
  __shared__ u16 sdst[CAP];    // 4 KB sorted dst
  __shared__ float wls[CAP];   // 8 KB sorted edge weights
  __shared__ int coff[NCLS + 1];
  __shared__ float s1l[32];
  __shared__ int cnt[32];
  __shared__ int off0[32];
  __shared__ int cur[32];
  const int b = blockIdx.x;
  const int t = threadIdx.x;

  if (t < 32) {
    cnt[t] = 0;
    const int nd = b * 32 + t;
    s1l[t] = (nd < NN) ? s1[nd] : 0.f;
  }
  if (t < NCLS) {  // 8-lane scan of per-class counts -> compaction offsets
    int c = bktcnt[b * NCLS + t];
    if (c > SUBCAP) c = SUBCAP;
    int xx = c;
#pragma unroll
    for (int o = 1; o < NCLS; o <<= 1) {
      const int y = __shfl_up(xx, o, NCLS);
      if (t >= o) xx += y;
    }
    coff[t] = xx - c;
    if (t == NCLS - 1) coff[NCLS] = xx;
  }
  __syncthreads();

  const int n = coff[NCLS];  // total edges this bucket (<= CAP)
  const u32* eb = binned + (size_t)b * CAP;
#pragma unroll
  for (int c = 0; c < NCLS; ++c) {
    const int base = coff[c];
    const int nc = coff[c + 1] - base;
    for (int i = t; i < nc; i += 256) ebuf[base + i] = eb[c * SUBCAP + i];
  }
  __syncthreads();

  for (int i = t; i < n; i += 256)
    atomicAdd(&cnt[(ebuf[i] >> 16) & 31], 1);
  __syncthreads();

  if (t < 32) {  // 32-wide inclusive shuffle scan
    const int v = cnt[t];
    int xx = v;
#pragma unroll
    for (int o = 1; o < 32; o <<= 1) {
      const int y = __shfl_up(xx, o, 32);
      if (t >= o) xx += y;
    }
    off0[t] = xx - v;  // exclusive prefix (preserved for agg)
    cur[t] = xx - v;   // scatter cursor
  }
  __syncthreads();

  for (int i = t; i < n; i += 256) {
    const u32 v = ebuf[i];
    const int ln = (v >> 16) & 31;
    const int d = (int)(v & 0xFFFFu);
    const int pos = atomicAdd(&cur[ln], 1);
    sdst[pos] = (u16)d;
    const float logit = s1l[ln] + s2[d];
    const float lr = logit > 0.f ? logit : ALPHA * logit;
    wls[pos] = __expf(-lr);
  }
  __syncthreads();

  // ---- agg phase: wave wv handles local nodes wv*8 .. wv*8+7 ----
  const int lane = t & 63;
  const int wv = t >> 6;       // 0..3
  const int g = lane >> 3;     // 8 edge-groups
  const int seg = lane & 7;    // 8 col-segments of 8

  for (int ni = 0; ni < 8; ++ni) {
    const int ln = wv * 8 + ni;          // 0..31
    const int node = b * 32 + ln;
    if (node >= NN) continue;  // wave-uniform (last bucket only)
    const int base = off0[ln];
    const int cend = base + cnt[ln];

    float a0 = 0.f, a1 = 0.f, a2 = 0.f, a3 = 0.f;
    float a4 = 0.f, a5 = 0.f, a6 = 0.f, a7 = 0.f;
    float wsum = 0.f;

    for (int e = base + g; e < cend; e += 8) {
      const int dg = sdst[e];        // same addr for 8 lanes -> LDS broadcast
      const float wg = wls[e];
      const uint4 p = *(const uint4*)(hb + (size_t)dg * OUTD + seg * 8);
      a0 = fmaf(wg, bflo(p.x), a0);
      a1 = fmaf(wg, bfhi(p.x), a1);
      a2 = fmaf(wg, bflo(p.y), a2);
      a3 = fmaf(wg, bfhi(p.y), a3);
      a4 = fmaf(wg, bflo(p.z), a4);
      a5 = fmaf(wg, bfhi(p.z), a5);
      a6 = fmaf(wg, bflo(p.w), a6);
      a7 = fmaf(wg, bfhi(p.w), a7);
      wsum += wg;
    }

#pragma unroll
    for (int off = 8; off <= 32; off <<= 1) {
      a0 += __shfl_xor(a0, off);
      a1 += __shfl_xor(a1, off);
      a2 += __shfl_xor(a2, off);
      a3 += __shfl_xor(a3, off);
      a4 += __shfl_xor(a4, off);
      a5 += __shfl_xor(a5, off);
      a6 += __shfl_xor(a6, off);
      a7 += __shfl_xor(a7, off);
      wsum += __shfl_xor(wsum, off);
    }

    if (g == 0) {
      const float inv = (cnt[ln] > 0) ? 1.f / wsum : 0.f;
      float4 r;
      float v;
      v = a0 * inv; r.x = v > 0.f ? v : (__expf(v) - 1.f);
      v = a1 * inv; r.y = v > 0.f ? v : (__expf(v) - 1.f);
      v = a2 * inv; r.z = v > 0.f ? v : (__expf(v) - 1.f);
      v = a3 * inv; r.w = v > 0.f ? v : (__expf(v) - 1.f);
      *(float4*)(out + (size_t)node * OUTD + seg * 8) = r;
      v = a4 * inv; r.x = v > 0.f ? v : (__expf(v) - 1.f);
      v = a5 * inv; r.y = v > 0.f ? v : (__expf(v) - 1.f);
      v = a6 * inv; r.z = v > 0.f ? v : (__expf(v) - 1.f);
      v = a7 * inv; r.w = v > 0.f ? v : (__expf(v) - 1.f);
      *(float4*)(out + (size_t)node * OUTD + seg * 8 + 4) = r;
    }
  }
}

// ---------------------------------------------------------------------------
extern "C" void kernel_launch(void* const* d_in, const int* in_sizes, int n_in,
                              void* d_out, int out_size, void* d_ws, size_t ws_size,
                              hipStream_t stream) {
  const float* x = (const float*)d_in[0];
  const int* ei = (const int*)d_in[1];
  const float* W = (const float*)d_in[2];
  const float* a = (const float*)d_in[3];
  float* out = (float*)d_out;

  // workspace layout (~20 MB)
  u16* hb = (u16*)d_ws;                          // NN*64 bf16 (6.4 MB)
  float* s1 = (float*)(hb + (size_t)NN * OUTD);  // NN
  float* s2 = s1 + NN;                           // NN
  int* bktcnt = (int*)(s2 + NN);                 // NB*NCLS (50 KB)
  u32* wt = (u32*)(bktcnt + NB * NCLS);          // 8192 (32 KB W^T bf16)
  u32* binned = wt + 8192;                       // NB*CAP u32 (12.8 MB)

  const int* src = ei;
  const int* dst = ei + NE;

  hipLaunchKernelGGL(init_kernel, dim3(ZB + 32), dim3(256), 0, stream,
                     W, wt, bktcnt);
  hipLaunchKernelGGL(gemm_kernel, dim3(GEMM_BLOCKS), dim3(256), 0, stream,
                     x, wt, a, hb, s1, s2);
  hipLaunchKernelGGL(bin_kernel, dim3(P1), dim3(256), 0, stream,
                     src, dst, bktcnt, binned);
  hipLaunchKernelGGL(bucket_agg_kernel, dim3(NB), dim3(256), 0, stream,
                     hb, s1, s2, bktcnt, binned, out);
}

// Round 12
// 162.732 us; speedup vs baseline: 1.1918x; 1.1918x over previous
//
#include <hip/hip_runtime.h>

#define NN 50000
#define NE 1600000
#define DIM 256
#define OUTD 64
#define ALPHA 0.2f

#define BSH 6                  // bucket = src >> 6 (64 nodes/bucket)
#define NB ((NN + 63) >> 6)    // 782 buckets
#define CAP 3072               // per-bucket capacity (mean 2048, sigma ~45)
#define P1 128                 // binning blocks (16-edge = 64B chunks, exclusive lines)
#define EPB (NE / P1)          // 12500 edges per block (div by 4)

#define GEMM_BLOCKS ((NN + 63) / 64)  // 782 (64 rows/block = 16 rows x 4 waves)
#define WSTRIDE 264            // Wl LDS row stride in u16 (256 + 8 pad)

typedef unsigned short u16;
typedef unsigned int u32;
typedef __attribute__((ext_vector_type(8))) short short8;   // 8 bf16 MFMA frag
typedef __attribute__((ext_vector_type(4))) float floatx4;  // MFMA accum

__device__ __forceinline__ u16 f2bf(float f) {
  u32 b = __float_as_uint(f);
  b += 0x7FFFu + ((b >> 16) & 1u);  // RNE
  return (u16)(b >> 16);
}
__device__ __forceinline__ float bflo(u32 u) { return __uint_as_float(u << 16); }
__device__ __forceinline__ float bfhi(u32 u) { return __uint_as_float(u & 0xFFFF0000u); }

// ---------------------------------------------------------------------------
// init: blocks 0..3 zero bucket counters; blocks 4..35 build W^T bf16 pairs
// (wt[n*128+kp] = {k=2kp lo, k=2kp+1 hi}).
// ---------------------------------------------------------------------------
__global__ __launch_bounds__(256) void init_kernel(const float* __restrict__ W,
                                                   u32* __restrict__ wt,
                                                   int* __restrict__ bktcnt) {
  if (blockIdx.x < 4) {
    const int i = blockIdx.x * 256 + threadIdx.x;
    if (i < NB) bktcnt[i] = 0;
    return;
  }
  const int g = (blockIdx.x - 4) * 256 + threadIdx.x;  // 0..8191
  const int n = g >> 7;
  const int kp = g & 127;
  const float lo = W[(size_t)(2 * kp) * OUTD + n];
  const float hi = W[(size_t)(2 * kp + 1) * OUTD + n];
  wt[g] = (u32)f2bf(lo) | ((u32)f2bf(hi) << 16);
}

// ---------------------------------------------------------------------------
// GEMM kernel (proven): bf16 MFMA h = x@W, packed bf16 out, s1/s2 epilogue.
// ---------------------------------------------------------------------------
__global__ __launch_bounds__(256) void gemm_kernel(
    const float* __restrict__ x, const u32* __restrict__ wt,
    const float* __restrict__ a, u16* __restrict__ hb,
    float* __restrict__ s1, float* __restrict__ s2)
{
  __shared__ u16 Wl[OUTD * WSTRIDE];  // 33 KB
  const int t = threadIdx.x;
  {  // stage W^T: 2048 uint4 chunks, coalesced global read, padded LDS write
    const uint4* srcv = (const uint4*)wt;
#pragma unroll
    for (int i = 0; i < 8; ++i) {
      const int c = t + 256 * i;
      const int n = c >> 5;
      const int k8 = c & 31;
      *(uint4*)&Wl[n * WSTRIDE + k8 * 8] = srcv[c];
    }
  }
  __syncthreads();

  const int lane = t & 63;
  const int wv = t >> 6;
  const int n = lane & 15;
  const int quad = lane >> 4;
  int rb = blockIdx.x * 64 + wv * 16;
  if (rb > NN - 16) rb = NN - 16;  // tail clamp (dup waves store identical)
  const int row = rb + n;
  const float4* xrow = (const float4*)(x + (size_t)row * DIM);

  floatx4 acc[4] = {{0.f, 0.f, 0.f, 0.f},
                    {0.f, 0.f, 0.f, 0.f},
                    {0.f, 0.f, 0.f, 0.f},
                    {0.f, 0.f, 0.f, 0.f}};

#pragma unroll
  for (int kk = 0; kk < 8; ++kk) {
    const float4 lo = xrow[kk * 8 + quad * 2];
    const float4 hi = xrow[kk * 8 + quad * 2 + 1];
    union { u32 u[4]; short8 s; } af;
    af.u[0] = (u32)f2bf(lo.x) | ((u32)f2bf(lo.y) << 16);
    af.u[1] = (u32)f2bf(lo.z) | ((u32)f2bf(lo.w) << 16);
    af.u[2] = (u32)f2bf(hi.x) | ((u32)f2bf(hi.y) << 16);
    af.u[3] = (u32)f2bf(hi.z) | ((u32)f2bf(hi.w) << 16);
#pragma unroll
    for (int nt = 0; nt < 4; ++nt) {
      const short8 bf =
          *(const short8*)&Wl[(nt * 16 + n) * WSTRIDE + kk * 32 + quad * 8];
      acc[nt] = __builtin_amdgcn_mfma_f32_16x16x32_bf16(af.s, bf, acc[nt], 0, 0, 0);
    }
  }

  float av1[4], av2[4];
#pragma unroll
  for (int nt = 0; nt < 4; ++nt) {
    av1[nt] = a[nt * 16 + n];
    av2[nt] = a[OUTD + nt * 16 + n];
  }

#pragma unroll
  for (int reg = 0; reg < 4; ++reg) {
    const int r = rb + quad * 4 + reg;
    float q1 = acc[0][reg] * av1[0] + acc[1][reg] * av1[1] +
               acc[2][reg] * av1[2] + acc[3][reg] * av1[3];
    float q2 = acc[0][reg] * av2[0] + acc[1][reg] * av2[1] +
               acc[2][reg] * av2[2] + acc[3][reg] * av2[3];
#pragma unroll
    for (int off = 1; off <= 8; off <<= 1) {
      q1 += __shfl_xor(q1, off);
      q2 += __shfl_xor(q2, off);
    }
    if (n == 0) { s1[r] = q1; s2[r] = q2; }
#pragma unroll
    for (int nt = 0; nt < 4; ++nt)
      hb[(size_t)r * OUTD + nt * 16 + n] = f2bf(acc[nt][reg]);
  }
}

// ---------------------------------------------------------------------------
// Bin kernel (proven round 8/9): chunk-reserved bucket binning, 1024
// thr/block, P1=128: 16-edge = 64B exclusive chunks (no cross-XCD bouncing).
// ---------------------------------------------------------------------------
__global__ __launch_bounds__(1024) void bin_kernel(
    const int* __restrict__ src, const int* __restrict__ dst,
    int* __restrict__ bktcnt, u32* __restrict__ binned)
{
  __shared__ int lh[NB];  // 3.1 KB
  const int t = threadIdx.x;
  const int p = blockIdx.x;
  for (int i = t; i < NB; i += 1024) lh[i] = 0;
  __syncthreads();

  const int4* src4 = (const int4*)(src + p * EPB);
  const int4* dst4 = (const int4*)(dst + p * EPB);
  for (int i = t; i < EPB / 4; i += 1024) {
    const int4 s = src4[i];
    if ((u32)s.x < (u32)NN) atomicAdd(&lh[s.x >> BSH], 1);
    if ((u32)s.y < (u32)NN) atomicAdd(&lh[s.y >> BSH], 1);
    if ((u32)s.z < (u32)NN) atomicAdd(&lh[s.z >> BSH], 1);
    if ((u32)s.w < (u32)NN) atomicAdd(&lh[s.w >> BSH], 1);
  }
  __syncthreads();

  // reserve a contiguous chunk per touched bucket; lh becomes the absolute
  // write cursor (b*CAP + base).
  for (int b = t; b < NB; b += 1024) {
    const int c = lh[b];
    lh[b] = (c > 0) ? atomicAdd(bktcnt + b, c) + b * CAP : 0;
  }
  __syncthreads();

  for (int i = t; i < EPB / 4; i += 1024) {
    const int4 s = src4[i];
    const int4 d = dst4[i];
    int pos, b;
    if ((u32)s.x < (u32)NN) {
      b = s.x >> BSH; pos = atomicAdd(&lh[b], 1);
      if (pos < (b + 1) * CAP) binned[pos] = ((u32)(s.x & 63) << 16) | (u32)(d.x & 0xFFFF);
    }
    if ((u32)s.y < (u32)NN) {
      b = s.y >> BSH; pos = atomicAdd(&lh[b], 1);
      if (pos < (b + 1) * CAP) binned[pos] = ((u32)(s.y & 63) << 16) | (u32)(d.y & 0xFFFF);
    }
    if ((u32)s.z < (u32)NN) {
      b = s.z >> BSH; pos = atomicAdd(&lh[b], 1);
      if (pos < (b + 1) * CAP) binned[pos] = ((u32)(s.z & 63) << 16) | (u32)(d.z & 0xFFFF);
    }
    if ((u32)s.w < (u32)NN) {
      b = s.w >> BSH; pos = atomicAdd(&lh[b], 1);
      if (pos < (b + 1) * CAP) binned[pos] = ((u32)(s.w & 63) << 16) | (u32)(d.w & 0xFFFF);
    }
  }
}

// ---------------------------------------------------------------------------
// Fused group+agg (round-9 champion, agg phase restructured for ILP):
// Phase 1 (unchanged): stage bucket in LDS, count, wave-0 scan, scatter with
//   fused weight exp.
// Phase 2 (NEW): deferred-reduce gather. Each wave owns 8 nodes, processed as
//   2 halves of 4: gather all 4 nodes' edges back-to-back into 4x9 register
//   accumulators with NO reduction in between (4 independent load chains ->
//   ~4x the outstanding loads per lane), then do the 4 shuffle-reduces.
//   Per-node accumulation order identical to round 9 (bitwise-same results).
// ---------------------------------------------------------------------------
__global__ __launch_bounds__(512) void bucket_agg_kernel(
    const u16* __restrict__ hb, const float* __restrict__ s1,
    const float* __restrict__ s2, const int* __restrict__ bktcnt,
    const u32* __restrict__ binned, float* __restrict__ out)
{
  __shared__ u32 ebuf[CAP];    // 12 KB staged bucket edges
  __shared__ u16 sdst[CAP];    // 6 KB sorted dst
  __shared__ float wls[CAP];   // 12 KB sorted edge weights
  __shared__ float s1l[64];
  __shared__ int cnt[64];
  __shared__ int off0[64];
  __shared__ int cur[64];
  const int b = blockIdx.x;
  const int t = threadIdx.x;
  int n = bktcnt[b];
  if (n > CAP) n = CAP;

  if (t < 64) {
    cnt[t] = 0;
    const int nd = b * 64 + t;
    s1l[t] = (nd < NN) ? s1[nd] : 0.f;
  }
  __syncthreads();

  const u32* eb = binned + (size_t)b * CAP;
  for (int i = t; i < n; i += 512) {
    const u32 v = eb[i];
    ebuf[i] = v;
    atomicAdd(&cnt[(v >> 16) & 63], 1);
  }
  __syncthreads();

  if (t < 64) {  // wave 0: inclusive shuffle scan over 64 counters
    const int v = cnt[t];
    int xx = v;
#pragma unroll
    for (int o = 1; o < 64; o <<= 1) {
      const int y = __shfl_up(xx, o, 64);
      if (t >= o) xx += y;
    }
    off0[t] = xx - v;  // exclusive prefix (preserved for agg)
    cur[t] = xx - v;   // scatter cursor
  }
  __syncthreads();

  for (int i = t; i < n; i += 512) {
    const u32 v = ebuf[i];
    const int ln = (v >> 16) & 63;
    const int d = (int)(v & 0xFFFFu);
    const int pos = atomicAdd(&cur[ln], 1);
    sdst[pos] = (u16)d;
    const float logit = s1l[ln] + s2[d];
    const float lr = logit > 0.f ? logit : ALPHA * logit;
    wls[pos] = __expf(-lr);
  }
  __syncthreads();

  // ---- agg phase (deferred-reduce): wave wv owns nodes wv*8 .. wv*8+7 ----
  const int lane = t & 63;
  const int wv = t >> 6;       // 0..7
  const int g = lane >> 3;     // 8 edge-groups
  const int seg = lane & 7;    // 8 col-segments of 8

#pragma unroll
  for (int half = 0; half < 2; ++half) {
    float acc[4][8];
    float ws[4];
#pragma unroll
    for (int q = 0; q < 4; ++q) {
      ws[q] = 0.f;
#pragma unroll
      for (int j = 0; j < 8; ++j) acc[q][j] = 0.f;
    }

    // gather 4 nodes back-to-back — independent load chains, no reduces
#pragma unroll
    for (int q = 0; q < 4; ++q) {
      const int ln = wv * 8 + half * 4 + q;
      const int base = off0[ln];
      const int cend = base + cnt[ln];
      for (int e = base + g; e < cend; e += 8) {
        const int dg = sdst[e];      // same addr for 8 lanes -> LDS broadcast
        const float wg = wls[e];
        const uint4 p = *(const uint4*)(hb + (size_t)dg * OUTD + seg * 8);
        acc[q][0] = fmaf(wg, bflo(p.x), acc[q][0]);
        acc[q][1] = fmaf(wg, bfhi(p.x), acc[q][1]);
        acc[q][2] = fmaf(wg, bflo(p.y), acc[q][2]);
        acc[q][3] = fmaf(wg, bfhi(p.y), acc[q][3]);
        acc[q][4] = fmaf(wg, bflo(p.z), acc[q][4]);
        acc[q][5] = fmaf(wg, bfhi(p.z), acc[q][5]);
        acc[q][6] = fmaf(wg, bflo(p.w), acc[q][6]);
        acc[q][7] = fmaf(wg, bfhi(p.w), acc[q][7]);
        ws[q] += wg;
      }
    }

    // now reduce + store the 4 nodes
#pragma unroll
    for (int q = 0; q < 4; ++q) {
      const int ln = wv * 8 + half * 4 + q;
      const int node = b * 64 + ln;
#pragma unroll
      for (int off = 8; off <= 32; off <<= 1) {
#pragma unroll
        for (int j = 0; j < 8; ++j) acc[q][j] += __shfl_xor(acc[q][j], off);
        ws[q] += __shfl_xor(ws[q], off);
      }
      if (g == 0 && node < NN) {
        const float inv = (cnt[ln] > 0) ? 1.f / ws[q] : 0.f;
        float4 r;
        float v;
        v = acc[q][0] * inv; r.x = v > 0.f ? v : (__expf(v) - 1.f);
        v = acc[q][1] * inv; r.y = v > 0.f ? v : (__expf(v) - 1.f);
        v = acc[q][2] * inv; r.z = v > 0.f ? v : (__expf(v) - 1.f);
        v = acc[q][3] * inv; r.w = v > 0.f ? v : (__expf(v) - 1.f);
        *(float4*)(out + (size_t)node * OUTD + seg * 8) = r;
        v = acc[q][4] * inv; r.x = v > 0.f ? v : (__expf(v) - 1.f);
        v = acc[q][5] * inv; r.y = v > 0.f ? v : (__expf(v) - 1.f);
        v = acc[q][6] * inv; r.z = v > 0.f ? v : (__expf(v) - 1.f);
        v = acc[q][7] * inv; r.w = v > 0.f ? v : (__expf(v) - 1.f);
        *(float4*)(out + (size_t)node * OUTD + seg * 8 + 4) = r;
      }
    }
  }
}

// ---------------------------------------------------------------------------
extern "C" void kernel_launch(void* const* d_in, const int* in_sizes, int n_in,
                              void* d_out, int out_size, void* d_ws, size_t ws_size,
                              hipStream_t stream) {
  const float* x = (const float*)d_in[0];
  const int* ei = (const int*)d_in[1];
  const float* W = (const float*)d_in[2];
  const float* a = (const float*)d_in[3];
  float* out = (float*)d_out;

  // workspace layout (~17 MB)
  u16* hb = (u16*)d_ws;                          // NN*64 bf16 (6.4 MB)
  float* s1 = (float*)(hb + (size_t)NN * OUTD);  // NN
  float* s2 = s1 + NN;                           // NN
  int* bktcnt = (int*)(s2 + NN);                 // NB
  u32* wt = (u32*)(bktcnt + NB);                 // 8192 (32 KB W^T bf16)
  u32* binned = wt + 8192;                       // NB*CAP u32 (9.6 MB)

  const int* src = ei;
  const int* dst = ei + NE;

  hipLaunchKernelGGL(init_kernel, dim3(36), dim3(256), 0, stream, W, wt, bktcnt);
  hipLaunchKernelGGL(gemm_kernel, dim3(GEMM_BLOCKS), dim3(256), 0, stream,
                     x, wt, a, hb, s1, s2);
  hipLaunchKernelGGL(bin_kernel, dim3(P1), dim3(1024), 0, stream,
                     src, dst, bktcnt, binned);
  hipLaunchKernelGGL(bucket_agg_kernel, dim3(NB), dim3(512), 0, stream,
                     hb, s1, s2, bktcnt, binned, out);
}

// Round 13
// 156.701 us; speedup vs baseline: 1.2377x; 1.0385x over previous
//
#include <hip/hip_runtime.h>

#define NN 50000
#define NE 1600000
#define DIM 256
#define OUTD 64
#define ALPHA 0.2f

#define BSH 6                  // bucket = src >> 6 (64 nodes/bucket)
#define NB ((NN + 63) >> 6)    // 782 buckets
#define CAP 3072               // per-bucket capacity (mean 2048, sigma ~45)
#define CAPH 1792              // per-half-bucket staging cap (mean 1024, +24s)
#define P1 128                 // binning blocks (16-edge = 64B chunks, exclusive lines)
#define EPB (NE / P1)          // 12500 edges per block (div by 4)

#define GB1024 ((NN + 255) / 256)  // 196 gemm blocks (256 rows = 16 waves x 16)
#define FAT_GRID (GB1024 + P1)     // 324
#define WSTRIDE 264            // Wl LDS row stride in u16 (256 + 8 pad)

typedef unsigned short u16;
typedef unsigned int u32;
typedef __attribute__((ext_vector_type(8))) short short8;   // 8 bf16 MFMA frag
typedef __attribute__((ext_vector_type(4))) float floatx4;  // MFMA accum

__device__ __forceinline__ u16 f2bf(float f) {
  u32 b = __float_as_uint(f);
  b += 0x7FFFu + ((b >> 16) & 1u);  // RNE
  return (u16)(b >> 16);
}
__device__ __forceinline__ float bflo(u32 u) { return __uint_as_float(u << 16); }
__device__ __forceinline__ float bfhi(u32 u) { return __uint_as_float(u & 0xFFFF0000u); }

// ---------------------------------------------------------------------------
// init: blocks 0..3 zero bucket counters; blocks 4..35 build W^T bf16 pairs
// (wt[n*128+kp] = {k=2kp lo, k=2kp+1 hi}).
// ---------------------------------------------------------------------------
__global__ __launch_bounds__(256) void init_kernel(const float* __restrict__ W,
                                                   u32* __restrict__ wt,
                                                   int* __restrict__ bktcnt) {
  if (blockIdx.x < 4) {
    const int i = blockIdx.x * 256 + threadIdx.x;
    if (i < NB) bktcnt[i] = 0;
    return;
  }
  const int g = (blockIdx.x - 4) * 256 + threadIdx.x;  // 0..8191
  const int n = g >> 7;
  const int kp = g & 127;
  const float lo = W[(size_t)(2 * kp) * OUTD + n];
  const float hi = W[(size_t)(2 * kp + 1) * OUTD + n];
  wt[g] = (u32)f2bf(lo) | ((u32)f2bf(hi) << 16);
}

// ---------------------------------------------------------------------------
// Fat kernel, 1024 threads uniform (no idle-thread barrier hazards):
//  blocks [0, GB1024): gemm — 16 waves x 16 rows = 256 rows/block, proven
//    MFMA inner loop per wave; W^T staged in 2 iterations.
//  blocks [GB1024, +P1): proven round-12 bin — chunk-reserved bucket binning,
//    P1=128 -> 16-edge = 64B exclusive chunks (no cross-XCD line bouncing).
// gemm finishes early and bin inherits the whole machine (r5/r7 overlap win).
// ---------------------------------------------------------------------------
__global__ __launch_bounds__(1024) void fat_kernel(
    const float* __restrict__ x, const u32* __restrict__ wt,
    const float* __restrict__ a, u16* __restrict__ hb,
    float* __restrict__ s1, float* __restrict__ s2,
    const int* __restrict__ src, const int* __restrict__ dst,
    int* __restrict__ bktcnt, u32* __restrict__ binned)
{
  __shared__ u16 Wl[OUTD * WSTRIDE];  // 33 KB (gemm path)
  int* lh = (int*)Wl;                 // bin path aliases (3.1 KB)
  const int t = threadIdx.x;

  if (blockIdx.x < GB1024) {
    // ---------------- GEMM path (proven inner loop, 16 waves) ----------------
    {  // stage W^T: 2048 uint4 chunks, 2 iterations at 1024 threads
      const uint4* srcv = (const uint4*)wt;
#pragma unroll
      for (int i = 0; i < 2; ++i) {
        const int c = t + 1024 * i;
        const int n = c >> 5;
        const int k8 = c & 31;
        *(uint4*)&Wl[n * WSTRIDE + k8 * 8] = srcv[c];
      }
    }
    __syncthreads();

    const int lane = t & 63;
    const int wv = t >> 6;           // 0..15
    const int n = lane & 15;
    const int quad = lane >> 4;
    int rb = blockIdx.x * 256 + wv * 16;
    if (rb > NN - 16) rb = NN - 16;  // tail clamp (dup waves store identical)
    const int row = rb + n;
    const float4* xrow = (const float4*)(x + (size_t)row * DIM);

    floatx4 acc[4] = {{0.f, 0.f, 0.f, 0.f},
                      {0.f, 0.f, 0.f, 0.f},
                      {0.f, 0.f, 0.f, 0.f},
                      {0.f, 0.f, 0.f, 0.f}};

#pragma unroll
    for (int kk = 0; kk < 8; ++kk) {
      const float4 lo = xrow[kk * 8 + quad * 2];
      const float4 hi = xrow[kk * 8 + quad * 2 + 1];
      union { u32 u[4]; short8 s; } af;
      af.u[0] = (u32)f2bf(lo.x) | ((u32)f2bf(lo.y) << 16);
      af.u[1] = (u32)f2bf(lo.z) | ((u32)f2bf(lo.w) << 16);
      af.u[2] = (u32)f2bf(hi.x) | ((u32)f2bf(hi.y) << 16);
      af.u[3] = (u32)f2bf(hi.z) | ((u32)f2bf(hi.w) << 16);
#pragma unroll
      for (int nt = 0; nt < 4; ++nt) {
        const short8 bf =
            *(const short8*)&Wl[(nt * 16 + n) * WSTRIDE + kk * 32 + quad * 8];
        acc[nt] = __builtin_amdgcn_mfma_f32_16x16x32_bf16(af.s, bf, acc[nt], 0, 0, 0);
      }
    }

    float av1[4], av2[4];
#pragma unroll
    for (int nt = 0; nt < 4; ++nt) {
      av1[nt] = a[nt * 16 + n];
      av2[nt] = a[OUTD + nt * 16 + n];
    }

#pragma unroll
    for (int reg = 0; reg < 4; ++reg) {
      const int r = rb + quad * 4 + reg;
      float q1 = acc[0][reg] * av1[0] + acc[1][reg] * av1[1] +
                 acc[2][reg] * av1[2] + acc[3][reg] * av1[3];
      float q2 = acc[0][reg] * av2[0] + acc[1][reg] * av2[1] +
                 acc[2][reg] * av2[2] + acc[3][reg] * av2[3];
#pragma unroll
      for (int off = 1; off <= 8; off <<= 1) {
        q1 += __shfl_xor(q1, off);
        q2 += __shfl_xor(q2, off);
      }
      if (n == 0) { s1[r] = q1; s2[r] = q2; }
#pragma unroll
      for (int nt = 0; nt < 4; ++nt)
        hb[(size_t)r * OUTD + nt * 16 + n] = f2bf(acc[nt][reg]);
    }
    return;
  }

  // ---------------- bin path (proven round 12, 1024 thr) ----------------
  const int p = blockIdx.x - GB1024;
  for (int i = t; i < NB; i += 1024) lh[i] = 0;
  __syncthreads();

  const int4* src4 = (const int4*)(src + p * EPB);
  const int4* dst4 = (const int4*)(dst + p * EPB);
  for (int i = t; i < EPB / 4; i += 1024) {
    const int4 s = src4[i];
    if ((u32)s.x < (u32)NN) atomicAdd(&lh[s.x >> BSH], 1);
    if ((u32)s.y < (u32)NN) atomicAdd(&lh[s.y >> BSH], 1);
    if ((u32)s.z < (u32)NN) atomicAdd(&lh[s.z >> BSH], 1);
    if ((u32)s.w < (u32)NN) atomicAdd(&lh[s.w >> BSH], 1);
  }
  __syncthreads();

  // reserve a contiguous chunk per touched bucket; lh becomes the absolute
  // write cursor (b*CAP + base).
  for (int b = t; b < NB; b += 1024) {
    const int c = lh[b];
    lh[b] = (c > 0) ? atomicAdd(bktcnt + b, c) + b * CAP : 0;
  }
  __syncthreads();

  for (int i = t; i < EPB / 4; i += 1024) {
    const int4 s = src4[i];
    const int4 d = dst4[i];
    int pos, b;
    if ((u32)s.x < (u32)NN) {
      b = s.x >> BSH; pos = atomicAdd(&lh[b], 1);
      if (pos < (b + 1) * CAP) binned[pos] = ((u32)(s.x & 63) << 16) | (u32)(d.x & 0xFFFF);
    }
    if ((u32)s.y < (u32)NN) {
      b = s.y >> BSH; pos = atomicAdd(&lh[b], 1);
      if (pos < (b + 1) * CAP) binned[pos] = ((u32)(s.y & 63) << 16) | (u32)(d.y & 0xFFFF);
    }
    if ((u32)s.z < (u32)NN) {
      b = s.z >> BSH; pos = atomicAdd(&lh[b], 1);
      if (pos < (b + 1) * CAP) binned[pos] = ((u32)(s.z & 63) << 16) | (u32)(d.z & 0xFFFF);
    }
    if ((u32)s.w < (u32)NN) {
      b = s.w >> BSH; pos = atomicAdd(&lh[b], 1);
      if (pos < (b + 1) * CAP) binned[pos] = ((u32)(s.w & 63) << 16) | (u32)(d.w & 0xFFFF);
    }
  }
}

// ---------------------------------------------------------------------------
// Fused group+agg, half-bucket blocks for occupancy: one 256-thread block per
// 32-node HALF of a 64-node bucket (grid 2*NB = 1564 -> ~6 blocks/CU vs 3).
// Stage-filter the bucket's edges for this half (LDS cursor), count, 32-wide
// scan, scatter with fused weight exp, then proven 4-wave x 8-node
// register-accumulator gather with LDS broadcast of (d, w). ~18 KB LDS.
// ---------------------------------------------------------------------------
__global__ __launch_bounds__(256) void bucket_agg_kernel(
    const u16* __restrict__ hb, const float* __restrict__ s1,
    const float* __restrict__ s2, const int* __restrict__ bktcnt,
    const u32* __restrict__ binned, float* __restrict__ out)
{
  __shared__ u32 ebuf[CAPH];   // 7 KB filtered half-bucket edges
  __shared__ u16 sdst[CAPH];   // 3.5 KB sorted dst
  __shared__ float wls[CAPH];  // 7 KB sorted edge weights
  __shared__ float s1l[32];
  __shared__ int cnt[32];
  __shared__ int off0[32];
  __shared__ int cur[32];
  __shared__ int ecur;
  const int b = blockIdx.x >> 1;        // bucket
  const int sub = blockIdx.x & 1;       // node half: 0 -> 0..31, 1 -> 32..63
  const int t = threadIdx.x;
  int n = bktcnt[b];
  if (n > CAP) n = CAP;

  if (t < 32) {
    cnt[t] = 0;
    const int nd = b * 64 + sub * 32 + t;
    s1l[t] = (nd < NN) ? s1[nd] : 0.f;
  }
  if (t == 0) ecur = 0;
  __syncthreads();

  // stage-filter: keep only this half's edges
  const u32* eb = binned + (size_t)b * CAP;
  for (int i = t; i < n; i += 256) {
    const u32 v = eb[i];
    const int ln = (v >> 16) & 63;
    if ((ln >> 5) == sub) {
      const int pos = atomicAdd(&ecur, 1);
      if (pos < CAPH) {
        ebuf[pos] = v;
        atomicAdd(&cnt[ln & 31], 1);
      }
    }
  }
  __syncthreads();

  int nh = ecur;
  if (nh > CAPH) nh = CAPH;

  if (t < 32) {  // 32-wide inclusive shuffle scan
    const int v = cnt[t];
    int xx = v;
#pragma unroll
    for (int o = 1; o < 32; o <<= 1) {
      const int y = __shfl_up(xx, o, 32);
      if (t >= o) xx += y;
    }
    off0[t] = xx - v;  // exclusive prefix (preserved for agg)
    cur[t] = xx - v;   // scatter cursor
  }
  __syncthreads();

  for (int i = t; i < nh; i += 256) {
    const u32 v = ebuf[i];
    const int ln = (v >> 16) & 31;
    const int d = (int)(v & 0xFFFFu);
    const int pos = atomicAdd(&cur[ln], 1);
    sdst[pos] = (u16)d;
    const float logit = s1l[ln] + s2[d];
    const float lr = logit > 0.f ? logit : ALPHA * logit;
    wls[pos] = __expf(-lr);
  }
  __syncthreads();

  // ---- agg phase: wave wv handles local nodes wv*8 .. wv*8+7 ----
  const int lane = t & 63;
  const int wv = t >> 6;       // 0..3
  const int g = lane >> 3;     // 8 edge-groups
  const int seg = lane & 7;    // 8 col-segments of 8

  for (int ni = 0; ni < 8; ++ni) {
    const int ln = wv * 8 + ni;                 // 0..31 (half-local)
    const int node = b * 64 + sub * 32 + ln;
    if (node >= NN) continue;  // wave-uniform (last bucket only)
    const int base = off0[ln];
    const int cend = base + cnt[ln];

    float a0 = 0.f, a1 = 0.f, a2 = 0.f, a3 = 0.f;
    float a4 = 0.f, a5 = 0.f, a6 = 0.f, a7 = 0.f;
    float wsum = 0.f;

    for (int e = base + g; e < cend; e += 8) {
      const int dg = sdst[e];        // same addr for 8 lanes -> LDS broadcast
      const float wg = wls[e];
      const uint4 p = *(const uint4*)(hb + (size_t)dg * OUTD + seg * 8);
      a0 = fmaf(wg, bflo(p.x), a0);
      a1 = fmaf(wg, bfhi(p.x), a1);
      a2 = fmaf(wg, bflo(p.y), a2);
      a3 = fmaf(wg, bfhi(p.y), a3);
      a4 = fmaf(wg, bflo(p.z), a4);
      a5 = fmaf(wg, bfhi(p.z), a5);
      a6 = fmaf(wg, bflo(p.w), a6);
      a7 = fmaf(wg, bfhi(p.w), a7);
      wsum += wg;
    }

#pragma unroll
    for (int off = 8; off <= 32; off <<= 1) {
      a0 += __shfl_xor(a0, off);
      a1 += __shfl_xor(a1, off);
      a2 += __shfl_xor(a2, off);
      a3 += __shfl_xor(a3, off);
      a4 += __shfl_xor(a4, off);
      a5 += __shfl_xor(a5, off);
      a6 += __shfl_xor(a6, off);
      a7 += __shfl_xor(a7, off);
      wsum += __shfl_xor(wsum, off);
    }

    if (g == 0) {
      const float inv = (cnt[ln] > 0) ? 1.f / wsum : 0.f;
      float4 r;
      float v;
      v = a0 * inv; r.x = v > 0.f ? v : (__expf(v) - 1.f);
      v = a1 * inv; r.y = v > 0.f ? v : (__expf(v) - 1.f);
      v = a2 * inv; r.z = v > 0.f ? v : (__expf(v) - 1.f);
      v = a3 * inv; r.w = v > 0.f ? v : (__expf(v) - 1.f);
      *(float4*)(out + (size_t)node * OUTD + seg * 8) = r;
      v = a4 * inv; r.x = v > 0.f ? v : (__expf(v) - 1.f);
      v = a5 * inv; r.y = v > 0.f ? v : (__expf(v) - 1.f);
      v = a6 * inv; r.z = v > 0.f ? v : (__expf(v) - 1.f);
      v = a7 * inv; r.w = v > 0.f ? v : (__expf(v) - 1.f);
      *(float4*)(out + (size_t)node * OUTD + seg * 8 + 4) = r;
    }
  }
}

// ---------------------------------------------------------------------------
extern "C" void kernel_launch(void* const* d_in, const int* in_sizes, int n_in,
                              void* d_out, int out_size, void* d_ws, size_t ws_size,
                              hipStream_t stream) {
  const float* x = (const float*)d_in[0];
  const int* ei = (const int*)d_in[1];
  const float* W = (const float*)d_in[2];
  const float* a = (const float*)d_in[3];
  float* out = (float*)d_out;

  // workspace layout (~17 MB)
  u16* hb = (u16*)d_ws;                          // NN*64 bf16 (6.4 MB)
  float* s1 = (float*)(hb + (size_t)NN * OUTD);  // NN
  float* s2 = s1 + NN;                           // NN
  int* bktcnt = (int*)(s2 + NN);                 // NB
  u32* wt = (u32*)(bktcnt + NB);                 // 8192 (32 KB W^T bf16)
  u32* binned = wt + 8192;                       // NB*CAP u32 (9.6 MB)

  const int* src = ei;
  const int* dst = ei + NE;

  hipLaunchKernelGGL(init_kernel, dim3(36), dim3(256), 0, stream, W, wt, bktcnt);
  hipLaunchKernelGGL(fat_kernel, dim3(FAT_GRID), dim3(1024), 0, stream,
                     x, wt, a, hb, s1, s2, src, dst, bktcnt, binned);
  hipLaunchKernelGGL(bucket_agg_kernel, dim3(2 * NB), dim3(256), 0, stream,
                     hb, s1, s2, bktcnt, binned, out);
}

// Round 14
// 154.482 us; speedup vs baseline: 1.2554x; 1.0144x over previous
//
#include <hip/hip_runtime.h>

#define NN 50000
#define NE 1600000
#define DIM 256
#define OUTD 64
#define ALPHA 0.2f

#define BSH 6                  // bucket = src >> 6 (64 nodes/bucket)
#define NB ((NN + 63) >> 6)    // 782 buckets
#define CAP 3072               // per-bucket capacity (mean 2048, sigma ~45)
#define CAPH 1792              // per-half-bucket staging cap (mean 1024, +24s)
#define P1 128                 // binning blocks (16-edge = 64B chunks, exclusive lines)
#define EPB (NE / P1)          // 12500 edges per block (div by 4)

#define GB1024 ((NN + 255) / 256)  // 196 gemm blocks (256 rows = 16 waves x 16)
#define FAT_GRID (GB1024 + P1)     // 324
#define WSTRIDE 264            // Wl LDS row stride in u16 (256 + 8 pad)

typedef unsigned short u16;
typedef unsigned int u32;
typedef __attribute__((ext_vector_type(8))) short short8;   // 8 bf16 MFMA frag
typedef __attribute__((ext_vector_type(4))) float floatx4;  // MFMA accum

__device__ __forceinline__ u16 f2bf(float f) {
  u32 b = __float_as_uint(f);
  b += 0x7FFFu + ((b >> 16) & 1u);  // RNE
  return (u16)(b >> 16);
}
__device__ __forceinline__ float bflo(u32 u) { return __uint_as_float(u << 16); }
__device__ __forceinline__ float bfhi(u32 u) { return __uint_as_float(u & 0xFFFF0000u); }

// ---------------------------------------------------------------------------
// init: blocks 0..3 zero bucket counters; blocks 4..35 build W^T bf16 pairs
// (wt[n*128+kp] = {k=2kp lo, k=2kp+1 hi}).
// ---------------------------------------------------------------------------
__global__ __launch_bounds__(256) void init_kernel(const float* __restrict__ W,
                                                   u32* __restrict__ wt,
                                                   int* __restrict__ bktcnt) {
  if (blockIdx.x < 4) {
    const int i = blockIdx.x * 256 + threadIdx.x;
    if (i < NB) bktcnt[i] = 0;
    return;
  }
  const int g = (blockIdx.x - 4) * 256 + threadIdx.x;  // 0..8191
  const int n = g >> 7;
  const int kp = g & 127;
  const float lo = W[(size_t)(2 * kp) * OUTD + n];
  const float hi = W[(size_t)(2 * kp + 1) * OUTD + n];
  wt[g] = (u32)f2bf(lo) | ((u32)f2bf(hi) << 16);
}

// ---------------------------------------------------------------------------
// Fat kernel, 1024 threads uniform (proven round 13):
//  blocks [0, GB1024): gemm — 16 waves x 16 rows = 256 rows/block.
//  blocks [GB1024, +P1): chunk-reserved bucket binning, P1=128.
// ---------------------------------------------------------------------------
__global__ __launch_bounds__(1024) void fat_kernel(
    const float* __restrict__ x, const u32* __restrict__ wt,
    const float* __restrict__ a, u16* __restrict__ hb,
    float* __restrict__ s1, float* __restrict__ s2,
    const int* __restrict__ src, const int* __restrict__ dst,
    int* __restrict__ bktcnt, u32* __restrict__ binned)
{
  __shared__ u16 Wl[OUTD * WSTRIDE];  // 33 KB (gemm path)
  int* lh = (int*)Wl;                 // bin path aliases (3.1 KB)
  const int t = threadIdx.x;

  if (blockIdx.x < GB1024) {
    // ---------------- GEMM path (proven inner loop, 16 waves) ----------------
    {  // stage W^T: 2048 uint4 chunks, 2 iterations at 1024 threads
      const uint4* srcv = (const uint4*)wt;
#pragma unroll
      for (int i = 0; i < 2; ++i) {
        const int c = t + 1024 * i;
        const int n = c >> 5;
        const int k8 = c & 31;
        *(uint4*)&Wl[n * WSTRIDE + k8 * 8] = srcv[c];
      }
    }
    __syncthreads();

    const int lane = t & 63;
    const int wv = t >> 6;           // 0..15
    const int n = lane & 15;
    const int quad = lane >> 4;
    int rb = blockIdx.x * 256 + wv * 16;
    if (rb > NN - 16) rb = NN - 16;  // tail clamp (dup waves store identical)
    const int row = rb + n;
    const float4* xrow = (const float4*)(x + (size_t)row * DIM);

    floatx4 acc[4] = {{0.f, 0.f, 0.f, 0.f},
                      {0.f, 0.f, 0.f, 0.f},
                      {0.f, 0.f, 0.f, 0.f},
                      {0.f, 0.f, 0.f, 0.f}};

#pragma unroll
    for (int kk = 0; kk < 8; ++kk) {
      const float4 lo = xrow[kk * 8 + quad * 2];
      const float4 hi = xrow[kk * 8 + quad * 2 + 1];
      union { u32 u[4]; short8 s; } af;
      af.u[0] = (u32)f2bf(lo.x) | ((u32)f2bf(lo.y) << 16);
      af.u[1] = (u32)f2bf(lo.z) | ((u32)f2bf(lo.w) << 16);
      af.u[2] = (u32)f2bf(hi.x) | ((u32)f2bf(hi.y) << 16);
      af.u[3] = (u32)f2bf(hi.z) | ((u32)f2bf(hi.w) << 16);
#pragma unroll
      for (int nt = 0; nt < 4; ++nt) {
        const short8 bf =
            *(const short8*)&Wl[(nt * 16 + n) * WSTRIDE + kk * 32 + quad * 8];
        acc[nt] = __builtin_amdgcn_mfma_f32_16x16x32_bf16(af.s, bf, acc[nt], 0, 0, 0);
      }
    }

    float av1[4], av2[4];
#pragma unroll
    for (int nt = 0; nt < 4; ++nt) {
      av1[nt] = a[nt * 16 + n];
      av2[nt] = a[OUTD + nt * 16 + n];
    }

#pragma unroll
    for (int reg = 0; reg < 4; ++reg) {
      const int r = rb + quad * 4 + reg;
      float q1 = acc[0][reg] * av1[0] + acc[1][reg] * av1[1] +
                 acc[2][reg] * av1[2] + acc[3][reg] * av1[3];
      float q2 = acc[0][reg] * av2[0] + acc[1][reg] * av2[1] +
                 acc[2][reg] * av2[2] + acc[3][reg] * av2[3];
#pragma unroll
      for (int off = 1; off <= 8; off <<= 1) {
        q1 += __shfl_xor(q1, off);
        q2 += __shfl_xor(q2, off);
      }
      if (n == 0) { s1[r] = q1; s2[r] = q2; }
#pragma unroll
      for (int nt = 0; nt < 4; ++nt)
        hb[(size_t)r * OUTD + nt * 16 + n] = f2bf(acc[nt][reg]);
    }
    return;
  }

  // ---------------- bin path (proven round 12, 1024 thr) ----------------
  const int p = blockIdx.x - GB1024;
  for (int i = t; i < NB; i += 1024) lh[i] = 0;
  __syncthreads();

  const int4* src4 = (const int4*)(src + p * EPB);
  const int4* dst4 = (const int4*)(dst + p * EPB);
  for (int i = t; i < EPB / 4; i += 1024) {
    const int4 s = src4[i];
    if ((u32)s.x < (u32)NN) atomicAdd(&lh[s.x >> BSH], 1);
    if ((u32)s.y < (u32)NN) atomicAdd(&lh[s.y >> BSH], 1);
    if ((u32)s.z < (u32)NN) atomicAdd(&lh[s.z >> BSH], 1);
    if ((u32)s.w < (u32)NN) atomicAdd(&lh[s.w >> BSH], 1);
  }
  __syncthreads();

  // reserve a contiguous chunk per touched bucket; lh becomes the absolute
  // write cursor (b*CAP + base).
  for (int b = t; b < NB; b += 1024) {
    const int c = lh[b];
    lh[b] = (c > 0) ? atomicAdd(bktcnt + b, c) + b * CAP : 0;
  }
  __syncthreads();

  for (int i = t; i < EPB / 4; i += 1024) {
    const int4 s = src4[i];
    const int4 d = dst4[i];
    int pos, b;
    if ((u32)s.x < (u32)NN) {
      b = s.x >> BSH; pos = atomicAdd(&lh[b], 1);
      if (pos < (b + 1) * CAP) binned[pos] = ((u32)(s.x & 63) << 16) | (u32)(d.x & 0xFFFF);
    }
    if ((u32)s.y < (u32)NN) {
      b = s.y >> BSH; pos = atomicAdd(&lh[b], 1);
      if (pos < (b + 1) * CAP) binned[pos] = ((u32)(s.y & 63) << 16) | (u32)(d.y & 0xFFFF);
    }
    if ((u32)s.z < (u32)NN) {
      b = s.z >> BSH; pos = atomicAdd(&lh[b], 1);
      if (pos < (b + 1) * CAP) binned[pos] = ((u32)(s.z & 63) << 16) | (u32)(d.z & 0xFFFF);
    }
    if ((u32)s.w < (u32)NN) {
      b = s.w >> BSH; pos = atomicAdd(&lh[b], 1);
      if (pos < (b + 1) * CAP) binned[pos] = ((u32)(s.w & 63) << 16) | (u32)(d.w & 0xFFFF);
    }
  }
}

// ---------------------------------------------------------------------------
// Fused group+agg, half-bucket blocks (proven round 13), agg inner loop now
// 4-deep unrolled: per main iteration, issue 4 LDS (d,w) pairs + 4
// independent 128B gathers back-to-back, then the 4 FMA blocks in original
// e-order (bitwise-identical accumulation). Mean degree 32 -> most nodes
// complete in one main iteration with 4 gathers in flight (was 1).
// ---------------------------------------------------------------------------
__global__ __launch_bounds__(256) void bucket_agg_kernel(
    const u16* __restrict__ hb, const float* __restrict__ s1,
    const float* __restrict__ s2, const int* __restrict__ bktcnt,
    const u32* __restrict__ binned, float* __restrict__ out)
{
  __shared__ u32 ebuf[CAPH];   // 7 KB filtered half-bucket edges
  __shared__ u16 sdst[CAPH];   // 3.5 KB sorted dst
  __shared__ float wls[CAPH];  // 7 KB sorted edge weights
  __shared__ float s1l[32];
  __shared__ int cnt[32];
  __shared__ int off0[32];
  __shared__ int cur[32];
  __shared__ int ecur;
  const int b = blockIdx.x >> 1;        // bucket
  const int sub = blockIdx.x & 1;       // node half: 0 -> 0..31, 1 -> 32..63
  const int t = threadIdx.x;
  int n = bktcnt[b];
  if (n > CAP) n = CAP;

  if (t < 32) {
    cnt[t] = 0;
    const int nd = b * 64 + sub * 32 + t;
    s1l[t] = (nd < NN) ? s1[nd] : 0.f;
  }
  if (t == 0) ecur = 0;
  __syncthreads();

  // stage-filter: keep only this half's edges
  const u32* eb = binned + (size_t)b * CAP;
  for (int i = t; i < n; i += 256) {
    const u32 v = eb[i];
    const int ln = (v >> 16) & 63;
    if ((ln >> 5) == sub) {
      const int pos = atomicAdd(&ecur, 1);
      if (pos < CAPH) {
        ebuf[pos] = v;
        atomicAdd(&cnt[ln & 31], 1);
      }
    }
  }
  __syncthreads();

  int nh = ecur;
  if (nh > CAPH) nh = CAPH;

  if (t < 32) {  // 32-wide inclusive shuffle scan
    const int v = cnt[t];
    int xx = v;
#pragma unroll
    for (int o = 1; o < 32; o <<= 1) {
      const int y = __shfl_up(xx, o, 32);
      if (t >= o) xx += y;
    }
    off0[t] = xx - v;  // exclusive prefix (preserved for agg)
    cur[t] = xx - v;   // scatter cursor
  }
  __syncthreads();

  for (int i = t; i < nh; i += 256) {
    const u32 v = ebuf[i];
    const int ln = (v >> 16) & 31;
    const int d = (int)(v & 0xFFFFu);
    const int pos = atomicAdd(&cur[ln], 1);
    sdst[pos] = (u16)d;
    const float logit = s1l[ln] + s2[d];
    const float lr = logit > 0.f ? logit : ALPHA * logit;
    wls[pos] = __expf(-lr);
  }
  __syncthreads();

  // ---- agg phase: wave wv handles local nodes wv*8 .. wv*8+7 ----
  const int lane = t & 63;
  const int wv = t >> 6;       // 0..3
  const int g = lane >> 3;     // 8 edge-groups
  const int seg = lane & 7;    // 8 col-segments of 8

  for (int ni = 0; ni < 8; ++ni) {
    const int ln = wv * 8 + ni;                 // 0..31 (half-local)
    const int node = b * 64 + sub * 32 + ln;
    if (node >= NN) continue;  // wave-uniform (last bucket only)
    const int base = off0[ln];
    const int cend = base + cnt[ln];

    float a0 = 0.f, a1 = 0.f, a2 = 0.f, a3 = 0.f;
    float a4 = 0.f, a5 = 0.f, a6 = 0.f, a7 = 0.f;
    float wsum = 0.f;

    int e = base + g;
    // 4-deep main loop: 4 independent gathers in flight per lane
    for (; e + 24 < cend; e += 32) {
      const int dg0 = sdst[e];       const float wg0 = wls[e];
      const int dg1 = sdst[e + 8];   const float wg1 = wls[e + 8];
      const int dg2 = sdst[e + 16];  const float wg2 = wls[e + 16];
      const int dg3 = sdst[e + 24];  const float wg3 = wls[e + 24];
      const uint4 p0 = *(const uint4*)(hb + (size_t)dg0 * OUTD + seg * 8);
      const uint4 p1 = *(const uint4*)(hb + (size_t)dg1 * OUTD + seg * 8);
      const uint4 p2 = *(const uint4*)(hb + (size_t)dg2 * OUTD + seg * 8);
      const uint4 p3 = *(const uint4*)(hb + (size_t)dg3 * OUTD + seg * 8);
      a0 = fmaf(wg0, bflo(p0.x), a0); a1 = fmaf(wg0, bfhi(p0.x), a1);
      a2 = fmaf(wg0, bflo(p0.y), a2); a3 = fmaf(wg0, bfhi(p0.y), a3);
      a4 = fmaf(wg0, bflo(p0.z), a4); a5 = fmaf(wg0, bfhi(p0.z), a5);
      a6 = fmaf(wg0, bflo(p0.w), a6); a7 = fmaf(wg0, bfhi(p0.w), a7);
      wsum += wg0;
      a0 = fmaf(wg1, bflo(p1.x), a0); a1 = fmaf(wg1, bfhi(p1.x), a1);
      a2 = fmaf(wg1, bflo(p1.y), a2); a3 = fmaf(wg1, bfhi(p1.y), a3);
      a4 = fmaf(wg1, bflo(p1.z), a4); a5 = fmaf(wg1, bfhi(p1.z), a5);
      a6 = fmaf(wg1, bflo(p1.w), a6); a7 = fmaf(wg1, bfhi(p1.w), a7);
      wsum += wg1;
      a0 = fmaf(wg2, bflo(p2.x), a0); a1 = fmaf(wg2, bfhi(p2.x), a1);
      a2 = fmaf(wg2, bflo(p2.y), a2); a3 = fmaf(wg2, bfhi(p2.y), a3);
      a4 = fmaf(wg2, bflo(p2.z), a4); a5 = fmaf(wg2, bfhi(p2.z), a5);
      a6 = fmaf(wg2, bflo(p2.w), a6); a7 = fmaf(wg2, bfhi(p2.w), a7);
      wsum += wg2;
      a0 = fmaf(wg3, bflo(p3.x), a0); a1 = fmaf(wg3, bfhi(p3.x), a1);
      a2 = fmaf(wg3, bflo(p3.y), a2); a3 = fmaf(wg3, bfhi(p3.y), a3);
      a4 = fmaf(wg3, bflo(p3.z), a4); a5 = fmaf(wg3, bfhi(p3.z), a5);
      a6 = fmaf(wg3, bflo(p3.w), a6); a7 = fmaf(wg3, bfhi(p3.w), a7);
      wsum += wg3;
    }
    for (; e < cend; e += 8) {
      const int dg = sdst[e];
      const float wg = wls[e];
      const uint4 p = *(const uint4*)(hb + (size_t)dg * OUTD + seg * 8);
      a0 = fmaf(wg, bflo(p.x), a0);
      a1 = fmaf(wg, bfhi(p.x), a1);
      a2 = fmaf(wg, bflo(p.y), a2);
      a3 = fmaf(wg, bfhi(p.y), a3);
      a4 = fmaf(wg, bflo(p.z), a4);
      a5 = fmaf(wg, bfhi(p.z), a5);
      a6 = fmaf(wg, bflo(p.w), a6);
      a7 = fmaf(wg, bfhi(p.w), a7);
      wsum += wg;
    }

#pragma unroll
    for (int off = 8; off <= 32; off <<= 1) {
      a0 += __shfl_xor(a0, off);
      a1 += __shfl_xor(a1, off);
      a2 += __shfl_xor(a2, off);
      a3 += __shfl_xor(a3, off);
      a4 += __shfl_xor(a4, off);
      a5 += __shfl_xor(a5, off);
      a6 += __shfl_xor(a6, off);
      a7 += __shfl_xor(a7, off);
      wsum += __shfl_xor(wsum, off);
    }

    if (g == 0) {
      const float inv = (cnt[ln] > 0) ? 1.f / wsum : 0.f;
      float4 r;
      float v;
      v = a0 * inv; r.x = v > 0.f ? v : (__expf(v) - 1.f);
      v = a1 * inv; r.y = v > 0.f ? v : (__expf(v) - 1.f);
      v = a2 * inv; r.z = v > 0.f ? v : (__expf(v) - 1.f);
      v = a3 * inv; r.w = v > 0.f ? v : (__expf(v) - 1.f);
      *(float4*)(out + (size_t)node * OUTD + seg * 8) = r;
      v = a4 * inv; r.x = v > 0.f ? v : (__expf(v) - 1.f);
      v = a5 * inv; r.y = v > 0.f ? v : (__expf(v) - 1.f);
      v = a6 * inv; r.z = v > 0.f ? v : (__expf(v) - 1.f);
      v = a7 * inv; r.w = v > 0.f ? v : (__expf(v) - 1.f);
      *(float4*)(out + (size_t)node * OUTD + seg * 8 + 4) = r;
    }
  }
}

// ---------------------------------------------------------------------------
extern "C" void kernel_launch(void* const* d_in, const int* in_sizes, int n_in,
                              void* d_out, int out_size, void* d_ws, size_t ws_size,
                              hipStream_t stream) {
  const float* x = (const float*)d_in[0];
  const int* ei = (const int*)d_in[1];
  const float* W = (const float*)d_in[2];
  const float* a = (const float*)d_in[3];
  float* out = (float*)d_out;

  // workspace layout (~17 MB)
  u16* hb = (u16*)d_ws;                          // NN*64 bf16 (6.4 MB)
  float* s1 = (float*)(hb + (size_t)NN * OUTD);  // NN
  float* s2 = s1 + NN;                           // NN
  int* bktcnt = (int*)(s2 + NN);                 // NB
  u32* wt = (u32*)(bktcnt + NB);                 // 8192 (32 KB W^T bf16)
  u32* binned = wt + 8192;                       // NB*CAP u32 (9.6 MB)

  const int* src = ei;
  const int* dst = ei + NE;

  hipLaunchKernelGGL(init_kernel, dim3(36), dim3(256), 0, stream, W, wt, bktcnt);
  hipLaunchKernelGGL(fat_kernel, dim3(FAT_GRID), dim3(1024), 0, stream,
                     x, wt, a, hb, s1, s2, src, dst, bktcnt, binned);
  hipLaunchKernelGGL(bucket_agg_kernel, dim3(2 * NB), dim3(256), 0, stream,
                     hb, s1, s2, bktcnt, binned, out);
}

// Round 15
// 151.743 us; speedup vs baseline: 1.2781x; 1.0181x over previous
//
#include <hip/hip_runtime.h>

#define NN 50000
#define NE 1600000
#define DIM 256
#define OUTD 64
#define ALPHA 0.2f

#define BSH 6                  // bucket = src >> 6 (64 nodes/bucket)
#define NB ((NN + 63) >> 6)    // 782 buckets
#define CAP 3072               // per-bucket capacity (mean 2048, sigma ~45)
#define CAPH 1792              // per-half-bucket staging cap (mean 1024, +24s)
#define P1 250                 // binning blocks (~8-edge = 33B chunks, ~2 writers/line;
                               // covers all 256 CUs in the bin tail — r14 fix)
#define EPB (NE / P1)          // 6400 edges per block (div by 4)

#define GB1024 ((NN + 255) / 256)  // 196 gemm blocks (256 rows = 16 waves x 16)
#define FAT_GRID (GB1024 + P1)     // 446
#define WSTRIDE 264            // Wl LDS row stride in u16 (256 + 8 pad)

typedef unsigned short u16;
typedef unsigned int u32;
typedef __attribute__((ext_vector_type(8))) short short8;   // 8 bf16 MFMA frag
typedef __attribute__((ext_vector_type(4))) float floatx4;  // MFMA accum

__device__ __forceinline__ u16 f2bf(float f) {
  u32 b = __float_as_uint(f);
  b += 0x7FFFu + ((b >> 16) & 1u);  // RNE
  return (u16)(b >> 16);
}
__device__ __forceinline__ float bflo(u32 u) { return __uint_as_float(u << 16); }
__device__ __forceinline__ float bfhi(u32 u) { return __uint_as_float(u & 0xFFFF0000u); }

// ---------------------------------------------------------------------------
// init: blocks 0..3 zero bucket counters; blocks 4..35 build W^T bf16 pairs
// (wt[n*128+kp] = {k=2kp lo, k=2kp+1 hi}).
// ---------------------------------------------------------------------------
__global__ __launch_bounds__(256) void init_kernel(const float* __restrict__ W,
                                                   u32* __restrict__ wt,
                                                   int* __restrict__ bktcnt) {
  if (blockIdx.x < 4) {
    const int i = blockIdx.x * 256 + threadIdx.x;
    if (i < NB) bktcnt[i] = 0;
    return;
  }
  const int g = (blockIdx.x - 4) * 256 + threadIdx.x;  // 0..8191
  const int n = g >> 7;
  const int kp = g & 127;
  const float lo = W[(size_t)(2 * kp) * OUTD + n];
  const float hi = W[(size_t)(2 * kp + 1) * OUTD + n];
  wt[g] = (u32)f2bf(lo) | ((u32)f2bf(hi) << 16);
}

// ---------------------------------------------------------------------------
// Fat kernel, 1024 threads uniform (proven round 13/14):
//  blocks [0, GB1024): gemm — 16 waves x 16 rows = 256 rows/block.
//  blocks [GB1024, +P1): chunk-reserved bucket binning, P1=250.
// ---------------------------------------------------------------------------
__global__ __launch_bounds__(1024) void fat_kernel(
    const float* __restrict__ x, const u32* __restrict__ wt,
    const float* __restrict__ a, u16* __restrict__ hb,
    float* __restrict__ s1, float* __restrict__ s2,
    const int* __restrict__ src, const int* __restrict__ dst,
    int* __restrict__ bktcnt, u32* __restrict__ binned)
{
  __shared__ u16 Wl[OUTD * WSTRIDE];  // 33 KB (gemm path)
  int* lh = (int*)Wl;                 // bin path aliases (3.1 KB)
  const int t = threadIdx.x;

  if (blockIdx.x < GB1024) {
    // ---------------- GEMM path (proven inner loop, 16 waves) ----------------
    {  // stage W^T: 2048 uint4 chunks, 2 iterations at 1024 threads
      const uint4* srcv = (const uint4*)wt;
#pragma unroll
      for (int i = 0; i < 2; ++i) {
        const int c = t + 1024 * i;
        const int n = c >> 5;
        const int k8 = c & 31;
        *(uint4*)&Wl[n * WSTRIDE + k8 * 8] = srcv[c];
      }
    }
    __syncthreads();

    const int lane = t & 63;
    const int wv = t >> 6;           // 0..15
    const int n = lane & 15;
    const int quad = lane >> 4;
    int rb = blockIdx.x * 256 + wv * 16;
    if (rb > NN - 16) rb = NN - 16;  // tail clamp (dup waves store identical)
    const int row = rb + n;
    const float4* xrow = (const float4*)(x + (size_t)row * DIM);

    floatx4 acc[4] = {{0.f, 0.f, 0.f, 0.f},
                      {0.f, 0.f, 0.f, 0.f},
                      {0.f, 0.f, 0.f, 0.f},
                      {0.f, 0.f, 0.f, 0.f}};

#pragma unroll
    for (int kk = 0; kk < 8; ++kk) {
      const float4 lo = xrow[kk * 8 + quad * 2];
      const float4 hi = xrow[kk * 8 + quad * 2 + 1];
      union { u32 u[4]; short8 s; } af;
      af.u[0] = (u32)f2bf(lo.x) | ((u32)f2bf(lo.y) << 16);
      af.u[1] = (u32)f2bf(lo.z) | ((u32)f2bf(lo.w) << 16);
      af.u[2] = (u32)f2bf(hi.x) | ((u32)f2bf(hi.y) << 16);
      af.u[3] = (u32)f2bf(hi.z) | ((u32)f2bf(hi.w) << 16);
#pragma unroll
      for (int nt = 0; nt < 4; ++nt) {
        const short8 bf =
            *(const short8*)&Wl[(nt * 16 + n) * WSTRIDE + kk * 32 + quad * 8];
        acc[nt] = __builtin_amdgcn_mfma_f32_16x16x32_bf16(af.s, bf, acc[nt], 0, 0, 0);
      }
    }

    float av1[4], av2[4];
#pragma unroll
    for (int nt = 0; nt < 4; ++nt) {
      av1[nt] = a[nt * 16 + n];
      av2[nt] = a[OUTD + nt * 16 + n];
    }

#pragma unroll
    for (int reg = 0; reg < 4; ++reg) {
      const int r = rb + quad * 4 + reg;
      float q1 = acc[0][reg] * av1[0] + acc[1][reg] * av1[1] +
                 acc[2][reg] * av1[2] + acc[3][reg] * av1[3];
      float q2 = acc[0][reg] * av2[0] + acc[1][reg] * av2[1] +
                 acc[2][reg] * av2[2] + acc[3][reg] * av2[3];
#pragma unroll
      for (int off = 1; off <= 8; off <<= 1) {
        q1 += __shfl_xor(q1, off);
        q2 += __shfl_xor(q2, off);
      }
      if (n == 0) { s1[r] = q1; s2[r] = q2; }
#pragma unroll
      for (int nt = 0; nt < 4; ++nt)
        hb[(size_t)r * OUTD + nt * 16 + n] = f2bf(acc[nt][reg]);
    }
    return;
  }

  // ---------------- bin path (proven structure, P1=250) ----------------
  const int p = blockIdx.x - GB1024;
  for (int i = t; i < NB; i += 1024) lh[i] = 0;
  __syncthreads();

  const int4* src4 = (const int4*)(src + p * EPB);
  const int4* dst4 = (const int4*)(dst + p * EPB);
  for (int i = t; i < EPB / 4; i += 1024) {
    const int4 s = src4[i];
    if ((u32)s.x < (u32)NN) atomicAdd(&lh[s.x >> BSH], 1);
    if ((u32)s.y < (u32)NN) atomicAdd(&lh[s.y >> BSH], 1);
    if ((u32)s.z < (u32)NN) atomicAdd(&lh[s.z >> BSH], 1);
    if ((u32)s.w < (u32)NN) atomicAdd(&lh[s.w >> BSH], 1);
  }
  __syncthreads();

  // reserve a contiguous chunk per touched bucket; lh becomes the absolute
  // write cursor (b*CAP + base).
  for (int b = t; b < NB; b += 1024) {
    const int c = lh[b];
    lh[b] = (c > 0) ? atomicAdd(bktcnt + b, c) + b * CAP : 0;
  }
  __syncthreads();

  for (int i = t; i < EPB / 4; i += 1024) {
    const int4 s = src4[i];
    const int4 d = dst4[i];
    int pos, b;
    if ((u32)s.x < (u32)NN) {
      b = s.x >> BSH; pos = atomicAdd(&lh[b], 1);
      if (pos < (b + 1) * CAP) binned[pos] = ((u32)(s.x & 63) << 16) | (u32)(d.x & 0xFFFF);
    }
    if ((u32)s.y < (u32)NN) {
      b = s.y >> BSH; pos = atomicAdd(&lh[b], 1);
      if (pos < (b + 1) * CAP) binned[pos] = ((u32)(s.y & 63) << 16) | (u32)(d.y & 0xFFFF);
    }
    if ((u32)s.z < (u32)NN) {
      b = s.z >> BSH; pos = atomicAdd(&lh[b], 1);
      if (pos < (b + 1) * CAP) binned[pos] = ((u32)(s.z & 63) << 16) | (u32)(d.z & 0xFFFF);
    }
    if ((u32)s.w < (u32)NN) {
      b = s.w >> BSH; pos = atomicAdd(&lh[b], 1);
      if (pos < (b + 1) * CAP) binned[pos] = ((u32)(s.w & 63) << 16) | (u32)(d.w & 0xFFFF);
    }
  }
}

// ---------------------------------------------------------------------------
// Fused group+agg, half-bucket blocks, 4-deep unrolled gather (round-14
// champion, unchanged).
// ---------------------------------------------------------------------------
__global__ __launch_bounds__(256) void bucket_agg_kernel(
    const u16* __restrict__ hb, const float* __restrict__ s1,
    const float* __restrict__ s2, const int* __restrict__ bktcnt,
    const u32* __restrict__ binned, float* __restrict__ out)
{
  __shared__ u32 ebuf[CAPH];   // 7 KB filtered half-bucket edges
  __shared__ u16 sdst[CAPH];   // 3.5 KB sorted dst
  __shared__ float wls[CAPH];  // 7 KB sorted edge weights
  __shared__ float s1l[32];
  __shared__ int cnt[32];
  __shared__ int off0[32];
  __shared__ int cur[32];
  __shared__ int ecur;
  const int b = blockIdx.x >> 1;        // bucket
  const int sub = blockIdx.x & 1;       // node half: 0 -> 0..31, 1 -> 32..63
  const int t = threadIdx.x;
  int n = bktcnt[b];
  if (n > CAP) n = CAP;

  if (t < 32) {
    cnt[t] = 0;
    const int nd = b * 64 + sub * 32 + t;
    s1l[t] = (nd < NN) ? s1[nd] : 0.f;
  }
  if (t == 0) ecur = 0;
  __syncthreads();

  // stage-filter: keep only this half's edges
  const u32* eb = binned + (size_t)b * CAP;
  for (int i = t; i < n; i += 256) {
    const u32 v = eb[i];
    const int ln = (v >> 16) & 63;
    if ((ln >> 5) == sub) {
      const int pos = atomicAdd(&ecur, 1);
      if (pos < CAPH) {
        ebuf[pos] = v;
        atomicAdd(&cnt[ln & 31], 1);
      }
    }
  }
  __syncthreads();

  int nh = ecur;
  if (nh > CAPH) nh = CAPH;

  if (t < 32) {  // 32-wide inclusive shuffle scan
    const int v = cnt[t];
    int xx = v;
#pragma unroll
    for (int o = 1; o < 32; o <<= 1) {
      const int y = __shfl_up(xx, o, 32);
      if (t >= o) xx += y;
    }
    off0[t] = xx - v;  // exclusive prefix (preserved for agg)
    cur[t] = xx - v;   // scatter cursor
  }
  __syncthreads();

  for (int i = t; i < nh; i += 256) {
    const u32 v = ebuf[i];
    const int ln = (v >> 16) & 31;
    const int d = (int)(v & 0xFFFFu);
    const int pos = atomicAdd(&cur[ln], 1);
    sdst[pos] = (u16)d;
    const float logit = s1l[ln] + s2[d];
    const float lr = logit > 0.f ? logit : ALPHA * logit;
    wls[pos] = __expf(-lr);
  }
  __syncthreads();

  // ---- agg phase: wave wv handles local nodes wv*8 .. wv*8+7 ----
  const int lane = t & 63;
  const int wv = t >> 6;       // 0..3
  const int g = lane >> 3;     // 8 edge-groups
  const int seg = lane & 7;    // 8 col-segments of 8

  for (int ni = 0; ni < 8; ++ni) {
    const int ln = wv * 8 + ni;                 // 0..31 (half-local)
    const int node = b * 64 + sub * 32 + ln;
    if (node >= NN) continue;  // wave-uniform (last bucket only)
    const int base = off0[ln];
    const int cend = base + cnt[ln];

    float a0 = 0.f, a1 = 0.f, a2 = 0.f, a3 = 0.f;
    float a4 = 0.f, a5 = 0.f, a6 = 0.f, a7 = 0.f;
    float wsum = 0.f;

    int e = base + g;
    // 4-deep main loop: 4 independent gathers in flight per lane
    for (; e + 24 < cend; e += 32) {
      const int dg0 = sdst[e];       const float wg0 = wls[e];
      const int dg1 = sdst[e + 8];   const float wg1 = wls[e + 8];
      const int dg2 = sdst[e + 16];  const float wg2 = wls[e + 16];
      const int dg3 = sdst[e + 24];  const float wg3 = wls[e + 24];
      const uint4 p0 = *(const uint4*)(hb + (size_t)dg0 * OUTD + seg * 8);
      const uint4 p1 = *(const uint4*)(hb + (size_t)dg1 * OUTD + seg * 8);
      const uint4 p2 = *(const uint4*)(hb + (size_t)dg2 * OUTD + seg * 8);
      const uint4 p3 = *(const uint4*)(hb + (size_t)dg3 * OUTD + seg * 8);
      a0 = fmaf(wg0, bflo(p0.x), a0); a1 = fmaf(wg0, bfhi(p0.x), a1);
      a2 = fmaf(wg0, bflo(p0.y), a2); a3 = fmaf(wg0, bfhi(p0.y), a3);
      a4 = fmaf(wg0, bflo(p0.z), a4); a5 = fmaf(wg0, bfhi(p0.z), a5);
      a6 = fmaf(wg0, bflo(p0.w), a6); a7 = fmaf(wg0, bfhi(p0.w), a7);
      wsum += wg0;
      a0 = fmaf(wg1, bflo(p1.x), a0); a1 = fmaf(wg1, bfhi(p1.x), a1);
      a2 = fmaf(wg1, bflo(p1.y), a2); a3 = fmaf(wg1, bfhi(p1.y), a3);
      a4 = fmaf(wg1, bflo(p1.z), a4); a5 = fmaf(wg1, bfhi(p1.z), a5);
      a6 = fmaf(wg1, bflo(p1.w), a6); a7 = fmaf(wg1, bfhi(p1.w), a7);
      wsum += wg1;
      a0 = fmaf(wg2, bflo(p2.x), a0); a1 = fmaf(wg2, bfhi(p2.x), a1);
      a2 = fmaf(wg2, bflo(p2.y), a2); a3 = fmaf(wg2, bfhi(p2.y), a3);
      a4 = fmaf(wg2, bflo(p2.z), a4); a5 = fmaf(wg2, bfhi(p2.z), a5);
      a6 = fmaf(wg2, bflo(p2.w), a6); a7 = fmaf(wg2, bfhi(p2.w), a7);
      wsum += wg2;
      a0 = fmaf(wg3, bflo(p3.x), a0); a1 = fmaf(wg3, bfhi(p3.x), a1);
      a2 = fmaf(wg3, bflo(p3.y), a2); a3 = fmaf(wg3, bfhi(p3.y), a3);
      a4 = fmaf(wg3, bflo(p3.z), a4); a5 = fmaf(wg3, bfhi(p3.z), a5);
      a6 = fmaf(wg3, bflo(p3.w), a6); a7 = fmaf(wg3, bfhi(p3.w), a7);
      wsum += wg3;
    }
    for (; e < cend; e += 8) {
      const int dg = sdst[e];
      const float wg = wls[e];
      const uint4 p = *(const uint4*)(hb + (size_t)dg * OUTD + seg * 8);
      a0 = fmaf(wg, bflo(p.x), a0);
      a1 = fmaf(wg, bfhi(p.x), a1);
      a2 = fmaf(wg, bflo(p.y), a2);
      a3 = fmaf(wg, bfhi(p.y), a3);
      a4 = fmaf(wg, bflo(p.z), a4);
      a5 = fmaf(wg, bfhi(p.z), a5);
      a6 = fmaf(wg, bflo(p.w), a6);
      a7 = fmaf(wg, bfhi(p.w), a7);
      wsum += wg;
    }

#pragma unroll
    for (int off = 8; off <= 32; off <<= 1) {
      a0 += __shfl_xor(a0, off);
      a1 += __shfl_xor(a1, off);
      a2 += __shfl_xor(a2, off);
      a3 += __shfl_xor(a3, off);
      a4 += __shfl_xor(a4, off);
      a5 += __shfl_xor(a5, off);
      a6 += __shfl_xor(a6, off);
      a7 += __shfl_xor(a7, off);
      wsum += __shfl_xor(wsum, off);
    }

    if (g == 0) {
      const float inv = (cnt[ln] > 0) ? 1.f / wsum : 0.f;
      float4 r;
      float v;
      v = a0 * inv; r.x = v > 0.f ? v : (__expf(v) - 1.f);
      v = a1 * inv; r.y = v > 0.f ? v : (__expf(v) - 1.f);
      v = a2 * inv; r.z = v > 0.f ? v : (__expf(v) - 1.f);
      v = a3 * inv; r.w = v > 0.f ? v : (__expf(v) - 1.f);
      *(float4*)(out + (size_t)node * OUTD + seg * 8) = r;
      v = a4 * inv; r.x = v > 0.f ? v : (__expf(v) - 1.f);
      v = a5 * inv; r.y = v > 0.f ? v : (__expf(v) - 1.f);
      v = a6 * inv; r.z = v > 0.f ? v : (__expf(v) - 1.f);
      v = a7 * inv; r.w = v > 0.f ? v : (__expf(v) - 1.f);
      *(float4*)(out + (size_t)node * OUTD + seg * 8 + 4) = r;
    }
  }
}

// ---------------------------------------------------------------------------
extern "C" void kernel_launch(void* const* d_in, const int* in_sizes, int n_in,
                              void* d_out, int out_size, void* d_ws, size_t ws_size,
                              hipStream_t stream) {
  const float* x = (const float*)d_in[0];
  const int* ei = (const int*)d_in[1];
  const float* W = (const float*)d_in[2];
  const float* a = (const float*)d_in[3];
  float* out = (float*)d_out;

  // workspace layout (~17 MB)
  u16* hb = (u16*)d_ws;                          // NN*64 bf16 (6.4 MB)
  float* s1 = (float*)(hb + (size_t)NN * OUTD);  // NN
  float* s2 = s1 + NN;                           // NN
  int* bktcnt = (int*)(s2 + NN);                 // NB
  u32* wt = (u32*)(bktcnt + NB);                 // 8192 (32 KB W^T bf16)
  u32* binned = wt + 8192;                       // NB*CAP u32 (9.6 MB)

  const int* src = ei;
  const int* dst = ei + NE;

  hipLaunchKernelGGL(init_kernel, dim3(36), dim3(256), 0, stream, W, wt, bktcnt);
  hipLaunchKernelGGL(fat_kernel, dim3(FAT_GRID), dim3(1024), 0, stream,
                     x, wt, a, hb, s1, s2, src, dst, bktcnt, binned);
  hipLaunchKernelGGL(bucket_agg_kernel, dim3(2 * NB), dim3(256), 0, stream,
                     hb, s1, s2, bktcnt, binned, out);
}

// Round 16
// 142.941 us; speedup vs baseline: 1.3568x; 1.0616x over previous
//
#include <hip/hip_runtime.h>

#define NN 50000
#define NE 1600000
#define DIM 256
#define OUTD 64
#define ALPHA 0.2f

#define BSH 6                  // bucket = src >> 6 (64 nodes/bucket)
#define NB ((NN + 63) >> 6)    // 782 buckets
#define CAP 3072               // per-bucket capacity (mean 2048, sigma ~45)
#define CAPH 1792              // per-half sorted cap (mean 1024, +24s)
#define P1 250                 // binning blocks (r15 proven: covers all CUs)
#define EPB (NE / P1)          // 6400 edges per block (div by 4)

#define GB1024 ((NN + 255) / 256)  // 196 gemm blocks (256 rows = 16 waves x 16)
#define FAT_GRID (GB1024 + P1)     // 446
#define WSTRIDE 264            // Wl LDS row stride in u16 (256 + 8 pad)

typedef unsigned short u16;
typedef unsigned int u32;
typedef __attribute__((ext_vector_type(8))) short short8;   // 8 bf16 MFMA frag
typedef __attribute__((ext_vector_type(4))) float floatx4;  // MFMA accum

__device__ __forceinline__ u16 f2bf(float f) {
  u32 b = __float_as_uint(f);
  b += 0x7FFFu + ((b >> 16) & 1u);  // RNE
  return (u16)(b >> 16);
}
__device__ __forceinline__ float bflo(u32 u) { return __uint_as_float(u << 16); }
__device__ __forceinline__ float bfhi(u32 u) { return __uint_as_float(u & 0xFFFF0000u); }

// ---------------------------------------------------------------------------
// init: blocks 0..3 zero bucket counters; blocks 4..35 build W^T bf16 pairs
// (wt[n*128+kp] = {k=2kp lo, k=2kp+1 hi}).
// ---------------------------------------------------------------------------
__global__ __launch_bounds__(256) void init_kernel(const float* __restrict__ W,
                                                   u32* __restrict__ wt,
                                                   int* __restrict__ bktcnt) {
  if (blockIdx.x < 4) {
    const int i = blockIdx.x * 256 + threadIdx.x;
    if (i < NB) bktcnt[i] = 0;
    return;
  }
  const int g = (blockIdx.x - 4) * 256 + threadIdx.x;  // 0..8191
  const int n = g >> 7;
  const int kp = g & 127;
  const float lo = W[(size_t)(2 * kp) * OUTD + n];
  const float hi = W[(size_t)(2 * kp + 1) * OUTD + n];
  wt[g] = (u32)f2bf(lo) | ((u32)f2bf(hi) << 16);
}

// ---------------------------------------------------------------------------
// Fat kernel, 1024 threads uniform (proven rounds 13-15):
//  blocks [0, GB1024): gemm — 16 waves x 16 rows = 256 rows/block.
//  blocks [GB1024, +P1): chunk-reserved bucket binning, P1=250.
// ---------------------------------------------------------------------------
__global__ __launch_bounds__(1024) void fat_kernel(
    const float* __restrict__ x, const u32* __restrict__ wt,
    const float* __restrict__ a, u16* __restrict__ hb,
    float* __restrict__ s1, float* __restrict__ s2,
    const int* __restrict__ src, const int* __restrict__ dst,
    int* __restrict__ bktcnt, u32* __restrict__ binned)
{
  __shared__ u16 Wl[OUTD * WSTRIDE];  // 33 KB (gemm path)
  int* lh = (int*)Wl;                 // bin path aliases (3.1 KB)
  const int t = threadIdx.x;

  if (blockIdx.x < GB1024) {
    // ---------------- GEMM path (proven inner loop, 16 waves) ----------------
    {  // stage W^T: 2048 uint4 chunks, 2 iterations at 1024 threads
      const uint4* srcv = (const uint4*)wt;
#pragma unroll
      for (int i = 0; i < 2; ++i) {
        const int c = t + 1024 * i;
        const int n = c >> 5;
        const int k8 = c & 31;
        *(uint4*)&Wl[n * WSTRIDE + k8 * 8] = srcv[c];
      }
    }
    __syncthreads();

    const int lane = t & 63;
    const int wv = t >> 6;           // 0..15
    const int n = lane & 15;
    const int quad = lane >> 4;
    int rb = blockIdx.x * 256 + wv * 16;
    if (rb > NN - 16) rb = NN - 16;  // tail clamp (dup waves store identical)
    const int row = rb + n;
    const float4* xrow = (const float4*)(x + (size_t)row * DIM);

    floatx4 acc[4] = {{0.f, 0.f, 0.f, 0.f},
                      {0.f, 0.f, 0.f, 0.f},
                      {0.f, 0.f, 0.f, 0.f},
                      {0.f, 0.f, 0.f, 0.f}};

#pragma unroll
    for (int kk = 0; kk < 8; ++kk) {
      const float4 lo = xrow[kk * 8 + quad * 2];
      const float4 hi = xrow[kk * 8 + quad * 2 + 1];
      union { u32 u[4]; short8 s; } af;
      af.u[0] = (u32)f2bf(lo.x) | ((u32)f2bf(lo.y) << 16);
      af.u[1] = (u32)f2bf(lo.z) | ((u32)f2bf(lo.w) << 16);
      af.u[2] = (u32)f2bf(hi.x) | ((u32)f2bf(hi.y) << 16);
      af.u[3] = (u32)f2bf(hi.z) | ((u32)f2bf(hi.w) << 16);
#pragma unroll
      for (int nt = 0; nt < 4; ++nt) {
        const short8 bf =
            *(const short8*)&Wl[(nt * 16 + n) * WSTRIDE + kk * 32 + quad * 8];
        acc[nt] = __builtin_amdgcn_mfma_f32_16x16x32_bf16(af.s, bf, acc[nt], 0, 0, 0);
      }
    }

    float av1[4], av2[4];
#pragma unroll
    for (int nt = 0; nt < 4; ++nt) {
      av1[nt] = a[nt * 16 + n];
      av2[nt] = a[OUTD + nt * 16 + n];
    }

#pragma unroll
    for (int reg = 0; reg < 4; ++reg) {
      const int r = rb + quad * 4 + reg;
      float q1 = acc[0][reg] * av1[0] + acc[1][reg] * av1[1] +
                 acc[2][reg] * av1[2] + acc[3][reg] * av1[3];
      float q2 = acc[0][reg] * av2[0] + acc[1][reg] * av2[1] +
                 acc[2][reg] * av2[2] + acc[3][reg] * av2[3];
#pragma unroll
      for (int off = 1; off <= 8; off <<= 1) {
        q1 += __shfl_xor(q1, off);
        q2 += __shfl_xor(q2, off);
      }
      if (n == 0) { s1[r] = q1; s2[r] = q2; }
#pragma unroll
      for (int nt = 0; nt < 4; ++nt)
        hb[(size_t)r * OUTD + nt * 16 + n] = f2bf(acc[nt][reg]);
    }
    return;
  }

  // ---------------- bin path (proven structure, P1=250) ----------------
  const int p = blockIdx.x - GB1024;
  for (int i = t; i < NB; i += 1024) lh[i] = 0;
  __syncthreads();

  const int4* src4 = (const int4*)(src + p * EPB);
  const int4* dst4 = (const int4*)(dst + p * EPB);
  for (int i = t; i < EPB / 4; i += 1024) {
    const int4 s = src4[i];
    if ((u32)s.x < (u32)NN) atomicAdd(&lh[s.x >> BSH], 1);
    if ((u32)s.y < (u32)NN) atomicAdd(&lh[s.y >> BSH], 1);
    if ((u32)s.z < (u32)NN) atomicAdd(&lh[s.z >> BSH], 1);
    if ((u32)s.w < (u32)NN) atomicAdd(&lh[s.w >> BSH], 1);
  }
  __syncthreads();

  // reserve a contiguous chunk per touched bucket; lh becomes the absolute
  // write cursor (b*CAP + base).
  for (int b = t; b < NB; b += 1024) {
    const int c = lh[b];
    lh[b] = (c > 0) ? atomicAdd(bktcnt + b, c) + b * CAP : 0;
  }
  __syncthreads();

  for (int i = t; i < EPB / 4; i += 1024) {
    const int4 s = src4[i];
    const int4 d = dst4[i];
    int pos, b;
    if ((u32)s.x < (u32)NN) {
      b = s.x >> BSH; pos = atomicAdd(&lh[b], 1);
      if (pos < (b + 1) * CAP) binned[pos] = ((u32)(s.x & 63) << 16) | (u32)(d.x & 0xFFFF);
    }
    if ((u32)s.y < (u32)NN) {
      b = s.y >> BSH; pos = atomicAdd(&lh[b], 1);
      if (pos < (b + 1) * CAP) binned[pos] = ((u32)(s.y & 63) << 16) | (u32)(d.y & 0xFFFF);
    }
    if ((u32)s.z < (u32)NN) {
      b = s.z >> BSH; pos = atomicAdd(&lh[b], 1);
      if (pos < (b + 1) * CAP) binned[pos] = ((u32)(s.z & 63) << 16) | (u32)(d.z & 0xFFFF);
    }
    if ((u32)s.w < (u32)NN) {
      b = s.w >> BSH; pos = atomicAdd(&lh[b], 1);
      if (pos < (b + 1) * CAP) binned[pos] = ((u32)(s.w & 63) << 16) | (u32)(d.w & 0xFFFF);
    }
  }
}

// ---------------------------------------------------------------------------
// Fused group+agg, half-bucket blocks, NODE-PER-GROUP gather (r16):
//  pass 1: count this half's edges per local node (read binned once).
//  scan (32-wide) -> off0/cur.
//  pass 2: re-read binned (L2-hot), scatter matching edges to sdst/wls with
//    fused weight exp. (No ebuf, no single-address ecur chain.)
//  gather: 8-lane group g of wave wv OWNS node wv*8+g and iterates its own
//    run sequentially (4-deep unrolled) — accumulators are complete per
//    group at loop end: ZERO shuffle reduces, all 64 lanes store.
// ---------------------------------------------------------------------------
__global__ __launch_bounds__(256) void bucket_agg_kernel(
    const u16* __restrict__ hb, const float* __restrict__ s1,
    const float* __restrict__ s2, const int* __restrict__ bktcnt,
    const u32* __restrict__ binned, float* __restrict__ out)
{
  __shared__ u16 sdst[CAPH];   // 3.5 KB sorted dst
  __shared__ float wls[CAPH];  // 7 KB sorted edge weights
  __shared__ float s1l[32];
  __shared__ int cnt[32];
  __shared__ int off0[32];
  __shared__ int cur[32];
  const int b = blockIdx.x >> 1;        // bucket
  const int sub = blockIdx.x & 1;       // node half: 0 -> 0..31, 1 -> 32..63
  const int t = threadIdx.x;
  int n = bktcnt[b];
  if (n > CAP) n = CAP;

  if (t < 32) {
    cnt[t] = 0;
    const int nd = b * 64 + sub * 32 + t;
    s1l[t] = (nd < NN) ? s1[nd] : 0.f;
  }
  __syncthreads();

  const u32* eb = binned + (size_t)b * CAP;
  // pass 1: count this half's edges per local node
  for (int i = t; i < n; i += 256) {
    const int ln6 = (eb[i] >> 16) & 63;
    if ((ln6 >> 5) == sub) atomicAdd(&cnt[ln6 & 31], 1);
  }
  __syncthreads();

  if (t < 32) {  // 32-wide inclusive shuffle scan
    const int v = cnt[t];
    int xx = v;
#pragma unroll
    for (int o = 1; o < 32; o <<= 1) {
      const int y = __shfl_up(xx, o, 32);
      if (t >= o) xx += y;
    }
    off0[t] = xx - v;  // exclusive prefix (preserved for gather)
    cur[t] = xx - v;   // scatter cursor
  }
  __syncthreads();

  // pass 2: scatter + fused weight exp (binned is L2-hot now)
  for (int i = t; i < n; i += 256) {
    const u32 v = eb[i];
    const int ln6 = (v >> 16) & 63;
    if ((ln6 >> 5) == sub) {
      const int ln = ln6 & 31;
      const int d = (int)(v & 0xFFFFu);
      const int pos = atomicAdd(&cur[ln], 1);
      if (pos < CAPH) {
        sdst[pos] = (u16)d;
        const float logit = s1l[ln] + s2[d];
        const float lr = logit > 0.f ? logit : ALPHA * logit;
        wls[pos] = __expf(-lr);
      }
    }
  }
  __syncthreads();

  // ---- gather: group owns one node; no cross-lane reduction needed ----
  const int lane = t & 63;
  const int wv = t >> 6;       // 0..3
  const int g = lane >> 3;     // group 0..7
  const int seg = lane & 7;    // col-segment of 8
  const int ln = wv * 8 + g;                  // 0..31 (half-local)
  const int node = b * 64 + sub * 32 + ln;
  const int base = off0[ln];
  int myc = cnt[ln];
  if (base >= CAPH) myc = 0;
  else if (base + myc > CAPH) myc = CAPH - base;

  float a0 = 0.f, a1 = 0.f, a2 = 0.f, a3 = 0.f;
  float a4 = 0.f, a5 = 0.f, a6 = 0.f, a7 = 0.f;
  float wsum = 0.f;

  int e = 0;
  // 4-deep main loop: 4 independent gathers in flight per lane
  for (; e + 3 < myc; e += 4) {
    const int dg0 = sdst[base + e];      const float wg0 = wls[base + e];
    const int dg1 = sdst[base + e + 1];  const float wg1 = wls[base + e + 1];
    const int dg2 = sdst[base + e + 2];  const float wg2 = wls[base + e + 2];
    const int dg3 = sdst[base + e + 3];  const float wg3 = wls[base + e + 3];
    const uint4 p0 = *(const uint4*)(hb + (size_t)dg0 * OUTD + seg * 8);
    const uint4 p1 = *(const uint4*)(hb + (size_t)dg1 * OUTD + seg * 8);
    const uint4 p2 = *(const uint4*)(hb + (size_t)dg2 * OUTD + seg * 8);
    const uint4 p3 = *(const uint4*)(hb + (size_t)dg3 * OUTD + seg * 8);
    a0 = fmaf(wg0, bflo(p0.x), a0); a1 = fmaf(wg0, bfhi(p0.x), a1);
    a2 = fmaf(wg0, bflo(p0.y), a2); a3 = fmaf(wg0, bfhi(p0.y), a3);
    a4 = fmaf(wg0, bflo(p0.z), a4); a5 = fmaf(wg0, bfhi(p0.z), a5);
    a6 = fmaf(wg0, bflo(p0.w), a6); a7 = fmaf(wg0, bfhi(p0.w), a7);
    wsum += wg0;
    a0 = fmaf(wg1, bflo(p1.x), a0); a1 = fmaf(wg1, bfhi(p1.x), a1);
    a2 = fmaf(wg1, bflo(p1.y), a2); a3 = fmaf(wg1, bfhi(p1.y), a3);
    a4 = fmaf(wg1, bflo(p1.z), a4); a5 = fmaf(wg1, bfhi(p1.z), a5);
    a6 = fmaf(wg1, bflo(p1.w), a6); a7 = fmaf(wg1, bfhi(p1.w), a7);
    wsum += wg1;
    a0 = fmaf(wg2, bflo(p2.x), a0); a1 = fmaf(wg2, bfhi(p2.x), a1);
    a2 = fmaf(wg2, bflo(p2.y), a2); a3 = fmaf(wg2, bfhi(p2.y), a3);
    a4 = fmaf(wg2, bflo(p2.z), a4); a5 = fmaf(wg2, bfhi(p2.z), a5);
    a6 = fmaf(wg2, bflo(p2.w), a6); a7 = fmaf(wg2, bfhi(p2.w), a7);
    wsum += wg2;
    a0 = fmaf(wg3, bflo(p3.x), a0); a1 = fmaf(wg3, bfhi(p3.x), a1);
    a2 = fmaf(wg3, bflo(p3.y), a2); a3 = fmaf(wg3, bfhi(p3.y), a3);
    a4 = fmaf(wg3, bflo(p3.z), a4); a5 = fmaf(wg3, bfhi(p3.z), a5);
    a6 = fmaf(wg3, bflo(p3.w), a6); a7 = fmaf(wg3, bfhi(p3.w), a7);
    wsum += wg3;
  }
  for (; e < myc; ++e) {
    const int dg = sdst[base + e];
    const float wg = wls[base + e];
    const uint4 p = *(const uint4*)(hb + (size_t)dg * OUTD + seg * 8);
    a0 = fmaf(wg, bflo(p.x), a0);
    a1 = fmaf(wg, bfhi(p.x), a1);
    a2 = fmaf(wg, bflo(p.y), a2);
    a3 = fmaf(wg, bfhi(p.y), a3);
    a4 = fmaf(wg, bflo(p.z), a4);
    a5 = fmaf(wg, bfhi(p.z), a5);
    a6 = fmaf(wg, bflo(p.w), a6);
    a7 = fmaf(wg, bfhi(p.w), a7);
    wsum += wg;
  }

  if (node < NN) {
    const float inv = (myc > 0) ? 1.f / wsum : 0.f;
    float4 r;
    float v;
    v = a0 * inv; r.x = v > 0.f ? v : (__expf(v) - 1.f);
    v = a1 * inv; r.y = v > 0.f ? v : (__expf(v) - 1.f);
    v = a2 * inv; r.z = v > 0.f ? v : (__expf(v) - 1.f);
    v = a3 * inv; r.w = v > 0.f ? v : (__expf(v) - 1.f);
    *(float4*)(out + (size_t)node * OUTD + seg * 8) = r;
    v = a4 * inv; r.x = v > 0.f ? v : (__expf(v) - 1.f);
    v = a5 * inv; r.y = v > 0.f ? v : (__expf(v) - 1.f);
    v = a6 * inv; r.z = v > 0.f ? v : (__expf(v) - 1.f);
    v = a7 * inv; r.w = v > 0.f ? v : (__expf(v) - 1.f);
    *(float4*)(out + (size_t)node * OUTD + seg * 8 + 4) = r;
  }
}

// ---------------------------------------------------------------------------
extern "C" void kernel_launch(void* const* d_in, const int* in_sizes, int n_in,
                              void* d_out, int out_size, void* d_ws, size_t ws_size,
                              hipStream_t stream) {
  const float* x = (const float*)d_in[0];
  const int* ei = (const int*)d_in[1];
  const float* W = (const float*)d_in[2];
  const float* a = (const float*)d_in[3];
  float* out = (float*)d_out;

  // workspace layout (~17 MB)
  u16* hb = (u16*)d_ws;                          // NN*64 bf16 (6.4 MB)
  float* s1 = (float*)(hb + (size_t)NN * OUTD);  // NN
  float* s2 = s1 + NN;                           // NN
  int* bktcnt = (int*)(s2 + NN);                 // NB
  u32* wt = (u32*)(bktcnt + NB);                 // 8192 (32 KB W^T bf16)
  u32* binned = wt + 8192;                       // NB*CAP u32 (9.6 MB)

  const int* src = ei;
  const int* dst = ei + NE;

  hipLaunchKernelGGL(init_kernel, dim3(36), dim3(256), 0, stream, W, wt, bktcnt);
  hipLaunchKernelGGL(fat_kernel, dim3(FAT_GRID), dim3(1024), 0, stream,
                     x, wt, a, hb, s1, s2, src, dst, bktcnt, binned);
  hipLaunchKernelGGL(bucket_agg_kernel, dim3(2 * NB), dim3(256), 0, stream,
                     hb, s1, s2, bktcnt, binned, out);
}

// Round 17
// 141.389 us; speedup vs baseline: 1.3717x; 1.0110x over previous
//
#include <hip/hip_runtime.h>

#define NN 50000
#define NE 1600000
#define DIM 256
#define OUTD 64
#define ALPHA 0.2f

#define BSH 6                  // bucket = src >> 6 (64 nodes/bucket)
#define NB ((NN + 63) >> 6)    // 782 buckets
#define CAP 3072               // per-bucket capacity (mean 2048, sigma ~45)
#define P1 250                 // binning blocks (r15 proven: covers all CUs)
#define EPB (NE / P1)          // 6400 edges per block (div by 4)

#define GB1024 ((NN + 255) / 256)  // 196 gemm blocks (256 rows = 16 waves x 16)
#define FAT_GRID (GB1024 + P1)     // 446
#define WSTRIDE 264            // Wl LDS row stride in u16 (256 + 8 pad)

typedef unsigned short u16;
typedef unsigned int u32;
typedef __attribute__((ext_vector_type(8))) short short8;   // 8 bf16 MFMA frag
typedef __attribute__((ext_vector_type(4))) float floatx4;  // MFMA accum

__device__ __forceinline__ u16 f2bf(float f) {
  u32 b = __float_as_uint(f);
  b += 0x7FFFu + ((b >> 16) & 1u);  // RNE
  return (u16)(b >> 16);
}
__device__ __forceinline__ float bflo(u32 u) { return __uint_as_float(u << 16); }
__device__ __forceinline__ float bfhi(u32 u) { return __uint_as_float(u & 0xFFFF0000u); }

// ---------------------------------------------------------------------------
// init: blocks 0..3 zero bucket counters; blocks 4..35 build W^T bf16 pairs
// (wt[n*128+kp] = {k=2kp lo, k=2kp+1 hi}).
// ---------------------------------------------------------------------------
__global__ __launch_bounds__(256) void init_kernel(const float* __restrict__ W,
                                                   u32* __restrict__ wt,
                                                   int* __restrict__ bktcnt) {
  if (blockIdx.x < 4) {
    const int i = blockIdx.x * 256 + threadIdx.x;
    if (i < NB) bktcnt[i] = 0;
    return;
  }
  const int g = (blockIdx.x - 4) * 256 + threadIdx.x;  // 0..8191
  const int n = g >> 7;
  const int kp = g & 127;
  const float lo = W[(size_t)(2 * kp) * OUTD + n];
  const float hi = W[(size_t)(2 * kp + 1) * OUTD + n];
  wt[g] = (u32)f2bf(lo) | ((u32)f2bf(hi) << 16);
}

// ---------------------------------------------------------------------------
// Fat kernel, 1024 threads uniform (proven rounds 13-15):
//  blocks [0, GB1024): gemm — 16 waves x 16 rows = 256 rows/block.
//  blocks [GB1024, +P1): chunk-reserved bucket binning, P1=250.
// ---------------------------------------------------------------------------
__global__ __launch_bounds__(1024) void fat_kernel(
    const float* __restrict__ x, const u32* __restrict__ wt,
    const float* __restrict__ a, u16* __restrict__ hb,
    float* __restrict__ s1, float* __restrict__ s2,
    const int* __restrict__ src, const int* __restrict__ dst,
    int* __restrict__ bktcnt, u32* __restrict__ binned)
{
  __shared__ u16 Wl[OUTD * WSTRIDE];  // 33 KB (gemm path)
  int* lh = (int*)Wl;                 // bin path aliases (3.1 KB)
  const int t = threadIdx.x;

  if (blockIdx.x < GB1024) {
    // ---------------- GEMM path (proven inner loop, 16 waves) ----------------
    {  // stage W^T: 2048 uint4 chunks, 2 iterations at 1024 threads
      const uint4* srcv = (const uint4*)wt;
#pragma unroll
      for (int i = 0; i < 2; ++i) {
        const int c = t + 1024 * i;
        const int n = c >> 5;
        const int k8 = c & 31;
        *(uint4*)&Wl[n * WSTRIDE + k8 * 8] = srcv[c];
      }
    }
    __syncthreads();

    const int lane = t & 63;
    const int wv = t >> 6;           // 0..15
    const int n = lane & 15;
    const int quad = lane >> 4;
    int rb = blockIdx.x * 256 + wv * 16;
    if (rb > NN - 16) rb = NN - 16;  // tail clamp (dup waves store identical)
    const int row = rb + n;
    const float4* xrow = (const float4*)(x + (size_t)row * DIM);

    floatx4 acc[4] = {{0.f, 0.f, 0.f, 0.f},
                      {0.f, 0.f, 0.f, 0.f},
                      {0.f, 0.f, 0.f, 0.f},
                      {0.f, 0.f, 0.f, 0.f}};

#pragma unroll
    for (int kk = 0; kk < 8; ++kk) {
      const float4 lo = xrow[kk * 8 + quad * 2];
      const float4 hi = xrow[kk * 8 + quad * 2 + 1];
      union { u32 u[4]; short8 s; } af;
      af.u[0] = (u32)f2bf(lo.x) | ((u32)f2bf(lo.y) << 16);
      af.u[1] = (u32)f2bf(lo.z) | ((u32)f2bf(lo.w) << 16);
      af.u[2] = (u32)f2bf(hi.x) | ((u32)f2bf(hi.y) << 16);
      af.u[3] = (u32)f2bf(hi.z) | ((u32)f2bf(hi.w) << 16);
#pragma unroll
      for (int nt = 0; nt < 4; ++nt) {
        const short8 bf =
            *(const short8*)&Wl[(nt * 16 + n) * WSTRIDE + kk * 32 + quad * 8];
        acc[nt] = __builtin_amdgcn_mfma_f32_16x16x32_bf16(af.s, bf, acc[nt], 0, 0, 0);
      }
    }

    float av1[4], av2[4];
#pragma unroll
    for (int nt = 0; nt < 4; ++nt) {
      av1[nt] = a[nt * 16 + n];
      av2[nt] = a[OUTD + nt * 16 + n];
    }

#pragma unroll
    for (int reg = 0; reg < 4; ++reg) {
      const int r = rb + quad * 4 + reg;
      float q1 = acc[0][reg] * av1[0] + acc[1][reg] * av1[1] +
                 acc[2][reg] * av1[2] + acc[3][reg] * av1[3];
      float q2 = acc[0][reg] * av2[0] + acc[1][reg] * av2[1] +
                 acc[2][reg] * av2[2] + acc[3][reg] * av2[3];
#pragma unroll
      for (int off = 1; off <= 8; off <<= 1) {
        q1 += __shfl_xor(q1, off);
        q2 += __shfl_xor(q2, off);
      }
      if (n == 0) { s1[r] = q1; s2[r] = q2; }
#pragma unroll
      for (int nt = 0; nt < 4; ++nt)
        hb[(size_t)r * OUTD + nt * 16 + n] = f2bf(acc[nt][reg]);
    }
    return;
  }

  // ---------------- bin path (proven structure, P1=250) ----------------
  const int p = blockIdx.x - GB1024;
  for (int i = t; i < NB; i += 1024) lh[i] = 0;
  __syncthreads();

  const int4* src4 = (const int4*)(src + p * EPB);
  const int4* dst4 = (const int4*)(dst + p * EPB);
  for (int i = t; i < EPB / 4; i += 1024) {
    const int4 s = src4[i];
    if ((u32)s.x < (u32)NN) atomicAdd(&lh[s.x >> BSH], 1);
    if ((u32)s.y < (u32)NN) atomicAdd(&lh[s.y >> BSH], 1);
    if ((u32)s.z < (u32)NN) atomicAdd(&lh[s.z >> BSH], 1);
    if ((u32)s.w < (u32)NN) atomicAdd(&lh[s.w >> BSH], 1);
  }
  __syncthreads();

  // reserve a contiguous chunk per touched bucket; lh becomes the absolute
  // write cursor (b*CAP + base).
  for (int b = t; b < NB; b += 1024) {
    const int c = lh[b];
    lh[b] = (c > 0) ? atomicAdd(bktcnt + b, c) + b * CAP : 0;
  }
  __syncthreads();

  for (int i = t; i < EPB / 4; i += 1024) {
    const int4 s = src4[i];
    const int4 d = dst4[i];
    int pos, b;
    if ((u32)s.x < (u32)NN) {
      b = s.x >> BSH; pos = atomicAdd(&lh[b], 1);
      if (pos < (b + 1) * CAP) binned[pos] = ((u32)(s.x & 63) << 16) | (u32)(d.x & 0xFFFF);
    }
    if ((u32)s.y < (u32)NN) {
      b = s.y >> BSH; pos = atomicAdd(&lh[b], 1);
      if (pos < (b + 1) * CAP) binned[pos] = ((u32)(s.y & 63) << 16) | (u32)(d.y & 0xFFFF);
    }
    if ((u32)s.z < (u32)NN) {
      b = s.z >> BSH; pos = atomicAdd(&lh[b], 1);
      if (pos < (b + 1) * CAP) binned[pos] = ((u32)(s.z & 63) << 16) | (u32)(d.z & 0xFFFF);
    }
    if ((u32)s.w < (u32)NN) {
      b = s.w >> BSH; pos = atomicAdd(&lh[b], 1);
      if (pos < (b + 1) * CAP) binned[pos] = ((u32)(s.w & 63) << 16) | (u32)(d.w & 0xFFFF);
    }
  }
}

// ---------------------------------------------------------------------------
// Fused group+agg (r17): one 512-thread block per FULL 64-node bucket.
// Single count pass + 64-wide wave-0 scan + single scatter pass (fused
// weight exp), then the r16 node-per-group gather: 8 waves x 8 groups = 64
// nodes, each 8-lane group owns one node and iterates its run 4-deep
// unrolled — zero shuffle reduces, all lanes store.
// vs r16: halves the redundant binned scans and count atomics (the
// half-bucket split made 2 blocks scan the same region twice each).
// ---------------------------------------------------------------------------
__global__ __launch_bounds__(512) void bucket_agg_kernel(
    const u16* __restrict__ hb, const float* __restrict__ s1,
    const float* __restrict__ s2, const int* __restrict__ bktcnt,
    const u32* __restrict__ binned, float* __restrict__ out)
{
  __shared__ u16 sdst[CAP];    // 6 KB sorted dst
  __shared__ float wls[CAP];   // 12 KB sorted edge weights
  __shared__ float s1l[64];
  __shared__ int cnt[64];
  __shared__ int off0[64];
  __shared__ int cur[64];
  const int b = blockIdx.x;
  const int t = threadIdx.x;
  int n = bktcnt[b];
  if (n > CAP) n = CAP;

  if (t < 64) {
    cnt[t] = 0;
    const int nd = b * 64 + t;
    s1l[t] = (nd < NN) ? s1[nd] : 0.f;
  }
  __syncthreads();

  const u32* eb = binned + (size_t)b * CAP;
  // pass 1: count edges per local node
  for (int i = t; i < n; i += 512)
    atomicAdd(&cnt[(eb[i] >> 16) & 63], 1);
  __syncthreads();

  if (t < 64) {  // wave 0: 64-wide inclusive shuffle scan
    const int v = cnt[t];
    int xx = v;
#pragma unroll
    for (int o = 1; o < 64; o <<= 1) {
      const int y = __shfl_up(xx, o, 64);
      if (t >= o) xx += y;
    }
    off0[t] = xx - v;  // exclusive prefix
    cur[t] = xx - v;   // scatter cursor
  }
  __syncthreads();

  // pass 2: scatter + fused weight exp (positions provably < n <= CAP)
  for (int i = t; i < n; i += 512) {
    const u32 v = eb[i];
    const int ln = (v >> 16) & 63;
    const int d = (int)(v & 0xFFFFu);
    const int pos = atomicAdd(&cur[ln], 1);
    sdst[pos] = (u16)d;
    const float logit = s1l[ln] + s2[d];
    const float lr = logit > 0.f ? logit : ALPHA * logit;
    wls[pos] = __expf(-lr);
  }
  __syncthreads();

  // ---- gather: group owns one node; no cross-lane reduction needed ----
  const int lane = t & 63;
  const int wv = t >> 6;       // 0..7
  const int g = lane >> 3;     // group 0..7
  const int seg = lane & 7;    // col-segment of 8
  const int ln = wv * 8 + g;   // 0..63
  const int node = b * 64 + ln;
  const int base = off0[ln];
  const int myc = cnt[ln];

  float a0 = 0.f, a1 = 0.f, a2 = 0.f, a3 = 0.f;
  float a4 = 0.f, a5 = 0.f, a6 = 0.f, a7 = 0.f;
  float wsum = 0.f;

  int e = 0;
  // 4-deep main loop: 4 independent gathers in flight per lane
  for (; e + 3 < myc; e += 4) {
    const int dg0 = sdst[base + e];      const float wg0 = wls[base + e];
    const int dg1 = sdst[base + e + 1];  const float wg1 = wls[base + e + 1];
    const int dg2 = sdst[base + e + 2];  const float wg2 = wls[base + e + 2];
    const int dg3 = sdst[base + e + 3];  const float wg3 = wls[base + e + 3];
    const uint4 p0 = *(const uint4*)(hb + (size_t)dg0 * OUTD + seg * 8);
    const uint4 p1 = *(const uint4*)(hb + (size_t)dg1 * OUTD + seg * 8);
    const uint4 p2 = *(const uint4*)(hb + (size_t)dg2 * OUTD + seg * 8);
    const uint4 p3 = *(const uint4*)(hb + (size_t)dg3 * OUTD + seg * 8);
    a0 = fmaf(wg0, bflo(p0.x), a0); a1 = fmaf(wg0, bfhi(p0.x), a1);
    a2 = fmaf(wg0, bflo(p0.y), a2); a3 = fmaf(wg0, bfhi(p0.y), a3);
    a4 = fmaf(wg0, bflo(p0.z), a4); a5 = fmaf(wg0, bfhi(p0.z), a5);
    a6 = fmaf(wg0, bflo(p0.w), a6); a7 = fmaf(wg0, bfhi(p0.w), a7);
    wsum += wg0;
    a0 = fmaf(wg1, bflo(p1.x), a0); a1 = fmaf(wg1, bfhi(p1.x), a1);
    a2 = fmaf(wg1, bflo(p1.y), a2); a3 = fmaf(wg1, bfhi(p1.y), a3);
    a4 = fmaf(wg1, bflo(p1.z), a4); a5 = fmaf(wg1, bfhi(p1.z), a5);
    a6 = fmaf(wg1, bflo(p1.w), a6); a7 = fmaf(wg1, bfhi(p1.w), a7);
    wsum += wg1;
    a0 = fmaf(wg2, bflo(p2.x), a0); a1 = fmaf(wg2, bfhi(p2.x), a1);
    a2 = fmaf(wg2, bflo(p2.y), a2); a3 = fmaf(wg2, bfhi(p2.y), a3);
    a4 = fmaf(wg2, bflo(p2.z), a4); a5 = fmaf(wg2, bfhi(p2.z), a5);
    a6 = fmaf(wg2, bflo(p2.w), a6); a7 = fmaf(wg2, bfhi(p2.w), a7);
    wsum += wg2;
    a0 = fmaf(wg3, bflo(p3.x), a0); a1 = fmaf(wg3, bfhi(p3.x), a1);
    a2 = fmaf(wg3, bflo(p3.y), a2); a3 = fmaf(wg3, bfhi(p3.y), a3);
    a4 = fmaf(wg3, bflo(p3.z), a4); a5 = fmaf(wg3, bfhi(p3.z), a5);
    a6 = fmaf(wg3, bflo(p3.w), a6); a7 = fmaf(wg3, bfhi(p3.w), a7);
    wsum += wg3;
  }
  for (; e < myc; ++e) {
    const int dg = sdst[base + e];
    const float wg = wls[base + e];
    const uint4 p = *(const uint4*)(hb + (size_t)dg * OUTD + seg * 8);
    a0 = fmaf(wg, bflo(p.x), a0);
    a1 = fmaf(wg, bfhi(p.x), a1);
    a2 = fmaf(wg, bflo(p.y), a2);
    a3 = fmaf(wg, bfhi(p.y), a3);
    a4 = fmaf(wg, bflo(p.z), a4);
    a5 = fmaf(wg, bfhi(p.z), a5);
    a6 = fmaf(wg, bflo(p.w), a6);
    a7 = fmaf(wg, bfhi(p.w), a7);
    wsum += wg;
  }

  if (node < NN) {
    const float inv = (myc > 0) ? 1.f / wsum : 0.f;
    float4 r;
    float v;
    v = a0 * inv; r.x = v > 0.f ? v : (__expf(v) - 1.f);
    v = a1 * inv; r.y = v > 0.f ? v : (__expf(v) - 1.f);
    v = a2 * inv; r.z = v > 0.f ? v : (__expf(v) - 1.f);
    v = a3 * inv; r.w = v > 0.f ? v : (__expf(v) - 1.f);
    *(float4*)(out + (size_t)node * OUTD + seg * 8) = r;
    v = a4 * inv; r.x = v > 0.f ? v : (__expf(v) - 1.f);
    v = a5 * inv; r.y = v > 0.f ? v : (__expf(v) - 1.f);
    v = a6 * inv; r.z = v > 0.f ? v : (__expf(v) - 1.f);
    v = a7 * inv; r.w = v > 0.f ? v : (__expf(v) - 1.f);
    *(float4*)(out + (size_t)node * OUTD + seg * 8 + 4) = r;
  }
}

// ---------------------------------------------------------------------------
extern "C" void kernel_launch(void* const* d_in, const int* in_sizes, int n_in,
                              void* d_out, int out_size, void* d_ws, size_t ws_size,
                              hipStream_t stream) {
  const float* x = (const float*)d_in[0];
  const int* ei = (const int*)d_in[1];
  const float* W = (const float*)d_in[2];
  const float* a = (const float*)d_in[3];
  float* out = (float*)d_out;

  // workspace layout (~17 MB)
  u16* hb = (u16*)d_ws;                          // NN*64 bf16 (6.4 MB)
  float* s1 = (float*)(hb + (size_t)NN * OUTD);  // NN
  float* s2 = s1 + NN;                           // NN
  int* bktcnt = (int*)(s2 + NN);                 // NB
  u32* wt = (u32*)(bktcnt + NB);                 // 8192 (32 KB W^T bf16)
  u32* binned = wt + 8192;                       // NB*CAP u32 (9.6 MB)

  const int* src = ei;
  const int* dst = ei + NE;

  hipLaunchKernelGGL(init_kernel, dim3(36), dim3(256), 0, stream, W, wt, bktcnt);
  hipLaunchKernelGGL(fat_kernel, dim3(FAT_GRID), dim3(1024), 0, stream,
                     x, wt, a, hb, s1, s2, src, dst, bktcnt, binned);
  hipLaunchKernelGGL(bucket_agg_kernel, dim3(NB), dim3(512), 0, stream,
                     hb, s1, s2, bktcnt, binned, out);
}

// Round 18
// 138.137 us; speedup vs baseline: 1.4040x; 1.0235x over previous
//
#include <hip/hip_runtime.h>

#define NN 50000
#define NE 1600000
#define DIM 256
#define OUTD 64
#define ALPHA 0.2f

#define BSH 6                  // bucket = src >> 6 (64 nodes/bucket)
#define NB ((NN + 63) >> 6)    // 782 buckets
#define CAP 3072               // per-bucket capacity (mean 2048, sigma ~45)
#define P1 250                 // binning blocks (r15 proven: covers all CUs)
#define EPB (NE / P1)          // 6400 edges per block (div by 4)

#define GB1024 ((NN + 255) / 256)  // 196 gemm blocks (256 rows = 16 waves x 16)
#define FAT_GRID (GB1024 + P1)     // 446
#define WSTRIDE 264            // Wl LDS row stride in u16 (256 + 8 pad)
// fat shared pool (u32 words): ebuf[EPB] + sorted[EPB] + scan[1024] + gbase[NB] + cur[NB]
#define SMEMW (2 * EPB + 1024 + 2 * NB)   // 15388 u32 = 61.5 KB

typedef unsigned short u16;
typedef unsigned int u32;
typedef __attribute__((ext_vector_type(8))) short short8;   // 8 bf16 MFMA frag
typedef __attribute__((ext_vector_type(4))) float floatx4;  // MFMA accum

__device__ __forceinline__ u16 f2bf(float f) {
  u32 b = __float_as_uint(f);
  b += 0x7FFFu + ((b >> 16) & 1u);  // RNE
  return (u16)(b >> 16);
}
__device__ __forceinline__ float bflo(u32 u) { return __uint_as_float(u << 16); }
__device__ __forceinline__ float bfhi(u32 u) { return __uint_as_float(u & 0xFFFF0000u); }

// ---------------------------------------------------------------------------
// init: blocks 0..3 zero bucket counters; blocks 4..35 build W^T bf16 pairs
// (wt[n*128+kp] = {k=2kp lo, k=2kp+1 hi}).
// ---------------------------------------------------------------------------
__global__ __launch_bounds__(256) void init_kernel(const float* __restrict__ W,
                                                   u32* __restrict__ wt,
                                                   int* __restrict__ bktcnt) {
  if (blockIdx.x < 4) {
    const int i = blockIdx.x * 256 + threadIdx.x;
    if (i < NB) bktcnt[i] = 0;
    return;
  }
  const int g = (blockIdx.x - 4) * 256 + threadIdx.x;  // 0..8191
  const int n = g >> 7;
  const int kp = g & 127;
  const float lo = W[(size_t)(2 * kp) * OUTD + n];
  const float hi = W[(size_t)(2 * kp + 1) * OUTD + n];
  wt[g] = (u32)f2bf(lo) | ((u32)f2bf(hi) << 16);
}

// ---------------------------------------------------------------------------
// Fat kernel, 1024 threads uniform:
//  blocks [0, GB1024): gemm — 16 waves x 16 rows = 256 rows/block (proven).
//  blocks [GB1024, +P1): bin — single-pass pack into LDS, block-local
//    count/scan/scatter (LDS sort), ONE chunk reservation per bucket, then
//    COALESCED contiguous chunk writes (~8x fewer write transactions than
//    the per-edge scattered writes of rounds 8-17).
// ---------------------------------------------------------------------------
__global__ __launch_bounds__(1024) void fat_kernel(
    const float* __restrict__ x, const u32* __restrict__ wt,
    const float* __restrict__ a, u16* __restrict__ hb,
    float* __restrict__ s1, float* __restrict__ s2,
    const int* __restrict__ src, const int* __restrict__ dst,
    int* __restrict__ bktcnt, u32* __restrict__ binned)
{
  __shared__ u32 smem[SMEMW];  // 61.5 KB pool; gemm aliases Wl (33 KB)
  u16* Wl = (u16*)smem;
  const int t = threadIdx.x;

  if (blockIdx.x < GB1024) {
    // ---------------- GEMM path (proven inner loop, 16 waves) ----------------
    {  // stage W^T: 2048 uint4 chunks, 2 iterations at 1024 threads
      const uint4* srcv = (const uint4*)wt;
#pragma unroll
      for (int i = 0; i < 2; ++i) {
        const int c = t + 1024 * i;
        const int n = c >> 5;
        const int k8 = c & 31;
        *(uint4*)&Wl[n * WSTRIDE + k8 * 8] = srcv[c];
      }
    }
    __syncthreads();

    const int lane = t & 63;
    const int wv = t >> 6;           // 0..15
    const int n = lane & 15;
    const int quad = lane >> 4;
    int rb = blockIdx.x * 256 + wv * 16;
    if (rb > NN - 16) rb = NN - 16;  // tail clamp (dup waves store identical)
    const int row = rb + n;
    const float4* xrow = (const float4*)(x + (size_t)row * DIM);

    floatx4 acc[4] = {{0.f, 0.f, 0.f, 0.f},
                      {0.f, 0.f, 0.f, 0.f},
                      {0.f, 0.f, 0.f, 0.f},
                      {0.f, 0.f, 0.f, 0.f}};

#pragma unroll
    for (int kk = 0; kk < 8; ++kk) {
      const float4 lo = xrow[kk * 8 + quad * 2];
      const float4 hi = xrow[kk * 8 + quad * 2 + 1];
      union { u32 u[4]; short8 s; } af;
      af.u[0] = (u32)f2bf(lo.x) | ((u32)f2bf(lo.y) << 16);
      af.u[1] = (u32)f2bf(lo.z) | ((u32)f2bf(lo.w) << 16);
      af.u[2] = (u32)f2bf(hi.x) | ((u32)f2bf(hi.y) << 16);
      af.u[3] = (u32)f2bf(hi.z) | ((u32)f2bf(hi.w) << 16);
#pragma unroll
      for (int nt = 0; nt < 4; ++nt) {
        const short8 bf =
            *(const short8*)&Wl[(nt * 16 + n) * WSTRIDE + kk * 32 + quad * 8];
        acc[nt] = __builtin_amdgcn_mfma_f32_16x16x32_bf16(af.s, bf, acc[nt], 0, 0, 0);
      }
    }

    float av1[4], av2[4];
#pragma unroll
    for (int nt = 0; nt < 4; ++nt) {
      av1[nt] = a[nt * 16 + n];
      av2[nt] = a[OUTD + nt * 16 + n];
    }

#pragma unroll
    for (int reg = 0; reg < 4; ++reg) {
      const int r = rb + quad * 4 + reg;
      float q1 = acc[0][reg] * av1[0] + acc[1][reg] * av1[1] +
                 acc[2][reg] * av1[2] + acc[3][reg] * av1[3];
      float q2 = acc[0][reg] * av2[0] + acc[1][reg] * av2[1] +
                 acc[2][reg] * av2[2] + acc[3][reg] * av2[3];
#pragma unroll
      for (int off = 1; off <= 8; off <<= 1) {
        q1 += __shfl_xor(q1, off);
        q2 += __shfl_xor(q2, off);
      }
      if (n == 0) { s1[r] = q1; s2[r] = q2; }
#pragma unroll
      for (int nt = 0; nt < 4; ++nt)
        hb[(size_t)r * OUTD + nt * 16 + n] = f2bf(acc[nt][reg]);
    }
    return;
  }

  // ---------------- bin path: LDS sort + coalesced chunk write ----------------
  const int p = blockIdx.x - GB1024;
  u32* ebuf = smem;                       // EPB packed (src<<16)|d
  u32* sorted = smem + EPB;               // EPB sorted
  int* scn = (int*)(smem + 2 * EPB);      // 1024 scan slots
  int* gbase = (int*)(smem + 2 * EPB + 1024);  // NB: global base - local excl
  int* cur = gbase + NB;                  // NB scatter cursors

  scn[t] = 0;
  __syncthreads();

  // single pass: pack edges into LDS + per-bucket count
  {
    const int4* src4 = (const int4*)(src + p * EPB);
    const int4* dst4 = (const int4*)(dst + p * EPB);
    for (int i = t; i < EPB / 4; i += 1024) {
      const int4 s = src4[i];
      const int4 d = dst4[i];
      u32 v0 = ((u32)s.x < (u32)NN) ? (((u32)s.x << 16) | ((u32)d.x & 0xFFFFu)) : 0xFFFFFFFFu;
      u32 v1 = ((u32)s.y < (u32)NN) ? (((u32)s.y << 16) | ((u32)d.y & 0xFFFFu)) : 0xFFFFFFFFu;
      u32 v2 = ((u32)s.z < (u32)NN) ? (((u32)s.z << 16) | ((u32)d.z & 0xFFFFu)) : 0xFFFFFFFFu;
      u32 v3 = ((u32)s.w < (u32)NN) ? (((u32)s.w << 16) | ((u32)d.w & 0xFFFFu)) : 0xFFFFFFFFu;
      ebuf[i * 4 + 0] = v0;
      ebuf[i * 4 + 1] = v1;
      ebuf[i * 4 + 2] = v2;
      ebuf[i * 4 + 3] = v3;
      if (v0 != 0xFFFFFFFFu) atomicAdd(&scn[v0 >> 22], 1);
      if (v1 != 0xFFFFFFFFu) atomicAdd(&scn[v1 >> 22], 1);
      if (v2 != 0xFFFFFFFFu) atomicAdd(&scn[v2 >> 22], 1);
      if (v3 != 0xFFFFFFFFu) atomicAdd(&scn[v3 >> 22], 1);
    }
  }
  __syncthreads();

  // block-wide inclusive scan over 1024 slots (Hillis-Steele)
  {
    int xx = scn[t];
    for (int o = 1; o < 1024; o <<= 1) {
      const int y = (t >= o) ? scn[t - o] : 0;
      __syncthreads();
      xx += y;
      scn[t] = xx;
      __syncthreads();
    }
  }

  // reserve one chunk per touched bucket; set cursors and write bases
  if (t < NB) {
    const int incl = scn[t];
    const int excl = (t > 0) ? scn[t - 1] : 0;
    const int c = incl - excl;
    cur[t] = excl;
    if (c > 0) {
      const int gb = atomicAdd(bktcnt + t, c) + t * CAP;
      gbase[t] = gb - excl;
    }
  }
  __syncthreads();

  // LDS scatter: sort edges by bucket
  for (int i = t; i < EPB; i += 1024) {
    const u32 v = ebuf[i];
    if (v != 0xFFFFFFFFu) {
      const int pos = atomicAdd(&cur[v >> 22], 1);
      sorted[pos] = v;
    }
  }
  __syncthreads();

  // coalesced chunk write: consecutive lanes hit consecutive global words
  const int total = scn[NB - 1];
  for (int i = t; i < total; i += 1024) {
    const u32 v = sorted[i];
    const int b = v >> 22;
    const int pos = gbase[b] + i;
    if (pos < (b + 1) * CAP)
      binned[pos] = (((v >> 16) & 63u) << 16) | (v & 0xFFFFu);
  }
}

// ---------------------------------------------------------------------------
// Fused group+agg (proven round 17): one 512-thread block per 64-node
// bucket. Count pass + 64-wide wave-0 scan + scatter pass (fused weight
// exp), then node-per-group gather: 8 waves x 8 groups = 64 nodes, 4-deep
// unrolled, zero shuffle reduces, all lanes store.
// ---------------------------------------------------------------------------
__global__ __launch_bounds__(512) void bucket_agg_kernel(
    const u16* __restrict__ hb, const float* __restrict__ s1,
    const float* __restrict__ s2, const int* __restrict__ bktcnt,
    const u32* __restrict__ binned, float* __restrict__ out)
{
  __shared__ u16 sdst[CAP];    // 6 KB sorted dst
  __shared__ float wls[CAP];   // 12 KB sorted edge weights
  __shared__ float s1l[64];
  __shared__ int cnt[64];
  __shared__ int off0[64];
  __shared__ int cur[64];
  const int b = blockIdx.x;
  const int t = threadIdx.x;
  int n = bktcnt[b];
  if (n > CAP) n = CAP;

  if (t < 64) {
    cnt[t] = 0;
    const int nd = b * 64 + t;
    s1l[t] = (nd < NN) ? s1[nd] : 0.f;
  }
  __syncthreads();

  const u32* eb = binned + (size_t)b * CAP;
  // pass 1: count edges per local node
  for (int i = t; i < n; i += 512)
    atomicAdd(&cnt[(eb[i] >> 16) & 63], 1);
  __syncthreads();

  if (t < 64) {  // wave 0: 64-wide inclusive shuffle scan
    const int v = cnt[t];
    int xx = v;
#pragma unroll
    for (int o = 1; o < 64; o <<= 1) {
      const int y = __shfl_up(xx, o, 64);
      if (t >= o) xx += y;
    }
    off0[t] = xx - v;  // exclusive prefix
    cur[t] = xx - v;   // scatter cursor
  }
  __syncthreads();

  // pass 2: scatter + fused weight exp (positions provably < n <= CAP)
  for (int i = t; i < n; i += 512) {
    const u32 v = eb[i];
    const int ln = (v >> 16) & 63;
    const int d = (int)(v & 0xFFFFu);
    const int pos = atomicAdd(&cur[ln], 1);
    sdst[pos] = (u16)d;
    const float logit = s1l[ln] + s2[d];
    const float lr = logit > 0.f ? logit : ALPHA * logit;
    wls[pos] = __expf(-lr);
  }
  __syncthreads();

  // ---- gather: group owns one node; no cross-lane reduction needed ----
  const int lane = t & 63;
  const int wv = t >> 6;       // 0..7
  const int g = lane >> 3;     // group 0..7
  const int seg = lane & 7;    // col-segment of 8
  const int ln = wv * 8 + g;   // 0..63
  const int node = b * 64 + ln;
  const int base = off0[ln];
  const int myc = cnt[ln];

  float a0 = 0.f, a1 = 0.f, a2 = 0.f, a3 = 0.f;
  float a4 = 0.f, a5 = 0.f, a6 = 0.f, a7 = 0.f;
  float wsum = 0.f;

  int e = 0;
  // 4-deep main loop: 4 independent gathers in flight per lane
  for (; e + 3 < myc; e += 4) {
    const int dg0 = sdst[base + e];      const float wg0 = wls[base + e];
    const int dg1 = sdst[base + e + 1];  const float wg1 = wls[base + e + 1];
    const int dg2 = sdst[base + e + 2];  const float wg2 = wls[base + e + 2];
    const int dg3 = sdst[base + e + 3];  const float wg3 = wls[base + e + 3];
    const uint4 p0 = *(const uint4*)(hb + (size_t)dg0 * OUTD + seg * 8);
    const uint4 p1 = *(const uint4*)(hb + (size_t)dg1 * OUTD + seg * 8);
    const uint4 p2 = *(const uint4*)(hb + (size_t)dg2 * OUTD + seg * 8);
    const uint4 p3 = *(const uint4*)(hb + (size_t)dg3 * OUTD + seg * 8);
    a0 = fmaf(wg0, bflo(p0.x), a0); a1 = fmaf(wg0, bfhi(p0.x), a1);
    a2 = fmaf(wg0, bflo(p0.y), a2); a3 = fmaf(wg0, bfhi(p0.y), a3);
    a4 = fmaf(wg0, bflo(p0.z), a4); a5 = fmaf(wg0, bfhi(p0.z), a5);
    a6 = fmaf(wg0, bflo(p0.w), a6); a7 = fmaf(wg0, bfhi(p0.w), a7);
    wsum += wg0;
    a0 = fmaf(wg1, bflo(p1.x), a0); a1 = fmaf(wg1, bfhi(p1.x), a1);
    a2 = fmaf(wg1, bflo(p1.y), a2); a3 = fmaf(wg1, bfhi(p1.y), a3);
    a4 = fmaf(wg1, bflo(p1.z), a4); a5 = fmaf(wg1, bfhi(p1.z), a5);
    a6 = fmaf(wg1, bflo(p1.w), a6); a7 = fmaf(wg1, bfhi(p1.w), a7);
    wsum += wg1;
    a0 = fmaf(wg2, bflo(p2.x), a0); a1 = fmaf(wg2, bfhi(p2.x), a1);
    a2 = fmaf(wg2, bflo(p2.y), a2); a3 = fmaf(wg2, bfhi(p2.y), a3);
    a4 = fmaf(wg2, bflo(p2.z), a4); a5 = fmaf(wg2, bfhi(p2.z), a5);
    a6 = fmaf(wg2, bflo(p2.w), a6); a7 = fmaf(wg2, bfhi(p2.w), a7);
    wsum += wg2;
    a0 = fmaf(wg3, bflo(p3.x), a0); a1 = fmaf(wg3, bfhi(p3.x), a1);
    a2 = fmaf(wg3, bflo(p3.y), a2); a3 = fmaf(wg3, bfhi(p3.y), a3);
    a4 = fmaf(wg3, bflo(p3.z), a4); a5 = fmaf(wg3, bfhi(p3.z), a5);
    a6 = fmaf(wg3, bflo(p3.w), a6); a7 = fmaf(wg3, bfhi(p3.w), a7);
    wsum += wg3;
  }
  for (; e < myc; ++e) {
    const int dg = sdst[base + e];
    const float wg = wls[base + e];
    const uint4 p = *(const uint4*)(hb + (size_t)dg * OUTD + seg * 8);
    a0 = fmaf(wg, bflo(p.x), a0);
    a1 = fmaf(wg, bfhi(p.x), a1);
    a2 = fmaf(wg, bflo(p.y), a2);
    a3 = fmaf(wg, bfhi(p.y), a3);
    a4 = fmaf(wg, bflo(p.z), a4);
    a5 = fmaf(wg, bfhi(p.z), a5);
    a6 = fmaf(wg, bflo(p.w), a6);
    a7 = fmaf(wg, bfhi(p.w), a7);
    wsum += wg;
  }

  if (node < NN) {
    const float inv = (myc > 0) ? 1.f / wsum : 0.f;
    float4 r;
    float v;
    v = a0 * inv; r.x = v > 0.f ? v : (__expf(v) - 1.f);
    v = a1 * inv; r.y = v > 0.f ? v : (__expf(v) - 1.f);
    v = a2 * inv; r.z = v > 0.f ? v : (__expf(v) - 1.f);
    v = a3 * inv; r.w = v > 0.f ? v : (__expf(v) - 1.f);
    *(float4*)(out + (size_t)node * OUTD + seg * 8) = r;
    v = a4 * inv; r.x = v > 0.f ? v : (__expf(v) - 1.f);
    v = a5 * inv; r.y = v > 0.f ? v : (__expf(v) - 1.f);
    v = a6 * inv; r.z = v > 0.f ? v : (__expf(v) - 1.f);
    v = a7 * inv; r.w = v > 0.f ? v : (__expf(v) - 1.f);
    *(float4*)(out + (size_t)node * OUTD + seg * 8 + 4) = r;
  }
}

// ---------------------------------------------------------------------------
extern "C" void kernel_launch(void* const* d_in, const int* in_sizes, int n_in,
                              void* d_out, int out_size, void* d_ws, size_t ws_size,
                              hipStream_t stream) {
  const float* x = (const float*)d_in[0];
  const int* ei = (const int*)d_in[1];
  const float* W = (const float*)d_in[2];
  const float* a = (const float*)d_in[3];
  float* out = (float*)d_out;

  // workspace layout (~17 MB)
  u16* hb = (u16*)d_ws;                          // NN*64 bf16 (6.4 MB)
  float* s1 = (float*)(hb + (size_t)NN * OUTD);  // NN
  float* s2 = s1 + NN;                           // NN
  int* bktcnt = (int*)(s2 + NN);                 // NB
  u32* wt = (u32*)(bktcnt + NB);                 // 8192 (32 KB W^T bf16)
  u32* binned = wt + 8192;                       // NB*CAP u32 (9.6 MB)

  const int* src = ei;
  const int* dst = ei + NE;

  hipLaunchKernelGGL(init_kernel, dim3(36), dim3(256), 0, stream, W, wt, bktcnt);
  hipLaunchKernelGGL(fat_kernel, dim3(FAT_GRID), dim3(1024), 0, stream,
                     x, wt, a, hb, s1, s2, src, dst, bktcnt, binned);
  hipLaunchKernelGGL(bucket_agg_kernel, dim3(NB), dim3(512), 0, stream,
                     hb, s1, s2, bktcnt, binned, out);
}